// Round 1
// baseline (3485.530 us; speedup 1.0000x reference)
//
#include <hip/hip_runtime.h>
#include <math.h>

#define N_NODES 50000
#define N_EDGES 1600000
#define F_DIM 1024
#define D_DIM 256
#define B_IDS 16384

static inline size_t alignup(size_t x) { return (x + 255) & ~(size_t)255; }

// ---------------- CSR build ----------------

__global__ void count_rows_k(const int* __restrict__ row, int* __restrict__ cnt, int E) {
  int i = blockIdx.x * blockDim.x + threadIdx.x;
  if (i < E) atomicAdd(&cnt[row[i]], 1);
}

__global__ void scan_k(const int* __restrict__ cnt, int* __restrict__ row_ptr, int n) {
  __shared__ int sums[1024];
  int t = threadIdx.x;
  int chunk = (n + 1023) >> 10;
  int start = t * chunk;
  int end = min(start + chunk, n);
  int s = 0;
  for (int i = start; i < end; ++i) s += cnt[i];
  sums[t] = s;
  __syncthreads();
  for (int off = 1; off < 1024; off <<= 1) {
    int v = (t >= off) ? sums[t - off] : 0;
    __syncthreads();
    sums[t] += v;
    __syncthreads();
  }
  int base = (t == 0) ? 0 : sums[t - 1];
  for (int i = start; i < end; ++i) { row_ptr[i] = base; base += cnt[i]; }
  if (t == 1023) row_ptr[n] = sums[1023];
}

__global__ void scatter_k(const int* __restrict__ row, const int* __restrict__ col,
                          const float* __restrict__ val, int* __restrict__ cursor,
                          int2* __restrict__ cv, int E) {
  int i = blockIdx.x * blockDim.x + threadIdx.x;
  if (i < E) {
    int pos = atomicAdd(&cursor[row[i]], 1);
    cv[pos] = make_int2(col[i], __float_as_int(val[i]));
  }
}

// ---------------- SpMM (CSR, one wave per row, 256-wide rows) ----------------

__global__ __launch_bounds__(256) void spmm_k(
    const int* __restrict__ row_ptr, const int2* __restrict__ cv,
    const float* __restrict__ src, float* __restrict__ dst,
    const float* __restrict__ bias, int do_leaky, int n)
{
  int r = (blockIdx.x << 2) + (threadIdx.x >> 6);
  if (r >= n) return;
  int lane = threadIdx.x & 63;
  int e0 = row_ptr[r], e1 = row_ptr[r + 1];
  float ax = 0.f, ay = 0.f, az = 0.f, aw = 0.f;
  for (int e = e0; e < e1; ++e) {
    int2 p = cv[e];
    float v = __int_as_float(p.y);
    const float4 x = *reinterpret_cast<const float4*>(src + (size_t)p.x * D_DIM + (lane << 2));
    ax = fmaf(v, x.x, ax);
    ay = fmaf(v, x.y, ay);
    az = fmaf(v, x.z, az);
    aw = fmaf(v, x.w, aw);
  }
  if (bias) {
    const float4 b = *reinterpret_cast<const float4*>(bias + (lane << 2));
    ax += b.x; ay += b.y; az += b.z; aw += b.w;
  }
  if (do_leaky) {
    ax = ax > 0.f ? ax : 0.01f * ax;
    ay = ay > 0.f ? ay : 0.01f * ay;
    az = az > 0.f ? az : 0.01f * az;
    aw = aw > 0.f ? aw : 0.01f * aw;
  }
  float4 o = make_float4(ax, ay, az, aw);
  *reinterpret_cast<float4*>(dst + (size_t)r * D_DIM + (lane << 2)) = o;
}

// ---------------- dense GEMM: C[M,64..256] = act(A[M,K] @ W[K,256] + b) ----------------
// MODE 0: C = A@W (+bias)          MODE 1: C = leaky(A@W + bias)
// MODE 2: g = sigmoid(A@W + bias); C = g*nxt + (1-g)*hin   (A==hin buffer semantics ok)

template<int MODE>
__global__ __launch_bounds__(256) void gemm_k(
    const float* __restrict__ Amat, int lda,
    const float* __restrict__ W, const float* __restrict__ bias,
    float* __restrict__ C, int ldc, int ccol0,
    int M, int K,
    const int* __restrict__ rowidx,
    const float* __restrict__ nxt, const float* __restrict__ hin)
{
  __shared__ float As[16][68];
  __shared__ float Ws[16][68];
  const int tid = threadIdx.x;
  const int tx = tid & 15, ty = tid >> 4;
  const int bm = blockIdx.y << 6;
  const int bn = blockIdx.x << 6;
  const int la_r = tid >> 2, la_k = (tid & 3) << 2;
  const int lw_k = tid >> 4, lw_c = (tid & 15) << 2;

  const float* arow = nullptr;
  {
    int gr = bm + la_r;
    if (gr < M) {
      int sr = rowidx ? rowidx[gr] : gr;
      arow = Amat + (size_t)sr * lda;
    }
  }

  float acc[4][4] = {{0.f}};
  for (int k0 = 0; k0 < K; k0 += 16) {
    float4 av = make_float4(0.f, 0.f, 0.f, 0.f);
    if (arow) av = *reinterpret_cast<const float4*>(arow + k0 + la_k);
    As[la_k + 0][la_r] = av.x;
    As[la_k + 1][la_r] = av.y;
    As[la_k + 2][la_r] = av.z;
    As[la_k + 3][la_r] = av.w;
    *reinterpret_cast<float4*>(&Ws[lw_k][lw_c]) =
        *reinterpret_cast<const float4*>(W + (size_t)(k0 + lw_k) * D_DIM + bn + lw_c);
    __syncthreads();
#pragma unroll
    for (int kk = 0; kk < 16; ++kk) {
      float4 a = *reinterpret_cast<const float4*>(&As[kk][ty << 2]);
      float4 b = *reinterpret_cast<const float4*>(&Ws[kk][tx << 2]);
      acc[0][0] = fmaf(a.x, b.x, acc[0][0]);
      acc[0][1] = fmaf(a.x, b.y, acc[0][1]);
      acc[0][2] = fmaf(a.x, b.z, acc[0][2]);
      acc[0][3] = fmaf(a.x, b.w, acc[0][3]);
      acc[1][0] = fmaf(a.y, b.x, acc[1][0]);
      acc[1][1] = fmaf(a.y, b.y, acc[1][1]);
      acc[1][2] = fmaf(a.y, b.z, acc[1][2]);
      acc[1][3] = fmaf(a.y, b.w, acc[1][3]);
      acc[2][0] = fmaf(a.z, b.x, acc[2][0]);
      acc[2][1] = fmaf(a.z, b.y, acc[2][1]);
      acc[2][2] = fmaf(a.z, b.z, acc[2][2]);
      acc[2][3] = fmaf(a.z, b.w, acc[2][3]);
      acc[3][0] = fmaf(a.w, b.x, acc[3][0]);
      acc[3][1] = fmaf(a.w, b.y, acc[3][1]);
      acc[3][2] = fmaf(a.w, b.z, acc[3][2]);
      acc[3][3] = fmaf(a.w, b.w, acc[3][3]);
    }
    __syncthreads();
  }

#pragma unroll
  for (int i = 0; i < 4; ++i) {
    int r = bm + (ty << 2) + i;
    if (r >= M) continue;
#pragma unroll
    for (int j = 0; j < 4; ++j) {
      int c = bn + (tx << 2) + j;
      float v = acc[i][j];
      if (bias) v += bias[c];
      if (MODE == 1) v = v > 0.f ? v : 0.01f * v;
      if (MODE == 2) {
        float g = 1.f / (1.f + __expf(-v));
        size_t idx = (size_t)r * D_DIM + c;
        C[idx] = g * nxt[idx] + (1.f - g) * hin[idx];
      } else {
        C[(size_t)r * ldc + ccol0 + c] = v;
      }
    }
  }
}

// ---------------- row gather into output columns ----------------

__global__ __launch_bounds__(256) void gather_k(const float* __restrict__ src,
                                                const int* __restrict__ ids,
                                                float* __restrict__ dst, int ccol0, int B)
{
  int i = (blockIdx.x << 2) + (threadIdx.x >> 6);
  if (i >= B) return;
  int lane = threadIdx.x & 63;
  const float4 v = *reinterpret_cast<const float4*>(src + (size_t)ids[i] * D_DIM + (lane << 2));
  *reinterpret_cast<float4*>(dst + (size_t)i * 1024 + ccol0 + (lane << 2)) = v;
}

// ---------------- launch ----------------

extern "C" void kernel_launch(void* const* d_in, const int* in_sizes, int n_in,
                              void* d_out, int out_size, void* d_ws, size_t ws_size,
                              hipStream_t stream)
{
  const float* ent_lit = (const float*)d_in[0];
  const float* rel_lit = (const float*)d_in[1];
  const float* attr_lit = (const float*)d_in[2];
  const float* ent_val = (const float*)d_in[3];
  const float* rel_val = (const float*)d_in[4];
  const float* attr_val = (const float*)d_in[5];
  const float* W_ent = (const float*)d_in[6];
  const float* b_ent = (const float*)d_in[7];
  const float* W_rel = (const float*)d_in[8];
  const float* b_rel = (const float*)d_in[9];
  const float* W_attr = (const float*)d_in[10];
  const float* b_attr = (const float*)d_in[11];
  const float* W_x = (const float*)d_in[12];
  const float* b_x = (const float*)d_in[13];
  const float* W_lit = (const float*)d_in[14];
  const float* b_lit = (const float*)d_in[15];
  const float* W_gate = (const float*)d_in[16];
  const float* b_gate = (const float*)d_in[17];
  const int* ent_row = (const int*)d_in[18];
  const int* ent_col = (const int*)d_in[19];
  const int* rel_row = (const int*)d_in[20];
  const int* rel_col = (const int*)d_in[21];
  const int* attr_row = (const int*)d_in[22];
  const int* attr_col = (const int*)d_in[23];
  const int* ent_ids = (const int*)d_in[24];
  float* out = (float*)d_out;

  char* p = (char*)d_ws;
  float* A = (float*)p; p += alignup((size_t)N_NODES * D_DIM * 4);
  float* S = (float*)p; p += alignup((size_t)N_NODES * D_DIM * 4);
  float* H = (float*)p; p += alignup((size_t)N_NODES * D_DIM * 4);
  int* row_ptr = (int*)p; p += alignup((size_t)(N_NODES + 1) * 4);
  int* cursor = (int*)p; p += alignup((size_t)N_NODES * 4);
  int2* cv = (int2*)p; p += alignup((size_t)N_EDGES * 8);
  if ((size_t)(p - (char*)d_ws) > ws_size) return;  // workspace too small: fail loudly

  dim3 blk(256);
  dim3 g_edges((N_EDGES + 255) / 256);
  dim3 g_spmm((N_NODES + 3) / 4);
  dim3 g_gather((B_IDS + 3) / 4);
  dim3 g_gemm_big(4, (N_NODES + 63) / 64);
  dim3 g_gemm_ids(4, (B_IDS + 63) / 64);

  auto build_csr = [&](const int* row, const int* col, const float* val) {
    hipMemsetAsync(cursor, 0, N_NODES * sizeof(int), stream);
    count_rows_k<<<g_edges, blk, 0, stream>>>(row, cursor, N_EDGES);
    scan_k<<<1, 1024, 0, stream>>>(cursor, row_ptr, N_NODES);
    hipMemcpyAsync(cursor, row_ptr, N_NODES * sizeof(int), hipMemcpyDeviceToDevice, stream);
    scatter_k<<<g_edges, blk, 0, stream>>>(row, col, val, cursor, cv, N_EDGES);
  };

  // ----- rel branch: leaky(spmm(rel, rel_lit@W_rel) + b_rel)[ent_ids] -> out[:,512:768]
  build_csr(rel_row, rel_col, rel_val);
  gemm_k<0><<<g_gemm_big, blk, 0, stream>>>(rel_lit, F_DIM, W_rel, nullptr, A, D_DIM, 0,
                                            N_NODES, F_DIM, nullptr, nullptr, nullptr);
  spmm_k<<<g_spmm, blk, 0, stream>>>(row_ptr, cv, A, S, b_rel, 1, N_NODES);
  gather_k<<<g_gather, blk, 0, stream>>>(S, ent_ids, out, 512, B_IDS);

  // ----- attr branch -> out[:,768:1024]
  build_csr(attr_row, attr_col, attr_val);
  gemm_k<0><<<g_gemm_big, blk, 0, stream>>>(attr_lit, F_DIM, W_attr, nullptr, A, D_DIM, 0,
                                            N_NODES, F_DIM, nullptr, nullptr, nullptr);
  spmm_k<<<g_spmm, blk, 0, stream>>>(row_ptr, cv, A, S, b_attr, 1, N_NODES);
  gather_k<<<g_gather, blk, 0, stream>>>(S, ent_ids, out, 768, B_IDS);

  // ----- ent literals: ent_lit[ent_ids] @ W_lit + b_lit -> out[:,0:256]
  gemm_k<0><<<g_gemm_ids, blk, 0, stream>>>(ent_lit, F_DIM, W_lit, b_lit, out, 1024, 0,
                                            B_IDS, F_DIM, ent_ids, nullptr, nullptr);

  // ----- ent n-hop -----
  build_csr(ent_row, ent_col, ent_val);
  gemm_k<0><<<g_gemm_big, blk, 0, stream>>>(ent_lit, F_DIM, W_ent, nullptr, A, D_DIM, 0,
                                            N_NODES, F_DIM, nullptr, nullptr, nullptr);
  spmm_k<<<g_spmm, blk, 0, stream>>>(row_ptr, cv, A, H, b_ent, 1, N_NODES);  // h1 -> H
  // hop 2: S_spmm=spmm(H); nxt=leaky(S@Wx+bx)->A; h2 = g*nxt+(1-g)*H -> S
  spmm_k<<<g_spmm, blk, 0, stream>>>(row_ptr, cv, H, S, nullptr, 0, N_NODES);
  gemm_k<1><<<g_gemm_big, blk, 0, stream>>>(S, D_DIM, W_x, b_x, A, D_DIM, 0,
                                            N_NODES, D_DIM, nullptr, nullptr, nullptr);
  gemm_k<2><<<g_gemm_big, blk, 0, stream>>>(H, D_DIM, W_gate, b_gate, S, D_DIM, 0,
                                            N_NODES, D_DIM, nullptr, A, H);
  // hop 3: spmm(S)->H; nxt=leaky(H@Wx+bx)->A; h3 = g*nxt+(1-g)*S -> H
  spmm_k<<<g_spmm, blk, 0, stream>>>(row_ptr, cv, S, H, nullptr, 0, N_NODES);
  gemm_k<1><<<g_gemm_big, blk, 0, stream>>>(H, D_DIM, W_x, b_x, A, D_DIM, 0,
                                            N_NODES, D_DIM, nullptr, nullptr, nullptr);
  gemm_k<2><<<g_gemm_big, blk, 0, stream>>>(S, D_DIM, W_gate, b_gate, H, D_DIM, 0,
                                            N_NODES, D_DIM, nullptr, A, S);
  gather_k<<<g_gather, blk, 0, stream>>>(H, ent_ids, out, 256, B_IDS);
}

// Round 5
// 2781.155 us; speedup vs baseline: 1.2533x; 1.2533x over previous
//
#include <hip/hip_runtime.h>
#include <math.h>

#define N_NODES 50000
#define N_EDGES 1600000
#define F_DIM 1024
#define D_DIM 256
#define B_IDS 16384

typedef __attribute__((ext_vector_type(8))) short bf16x8;
typedef __attribute__((ext_vector_type(4))) float f32x4;

static inline size_t alignup(size_t x) { return (x + 255) & ~(size_t)255; }

__device__ inline unsigned short f2bf(float f) {
  unsigned u = __float_as_uint(f);
  u += 0x7fffu + ((u >> 16) & 1u);   // RNE (inputs are finite)
  return (unsigned short)(u >> 16);
}
__device__ inline float bf2f(unsigned short u) {
  return __uint_as_float(((unsigned)u) << 16);
}

// ---- weight transpose + bf16 hi/lo split: Wt_hi/lo[n][k] from W[k][n] ----
__global__ __launch_bounds__(256) void tr_k(const float* __restrict__ W,
                                            unsigned short* __restrict__ Wt_hi,
                                            unsigned short* __restrict__ Wt_lo, int K) {
  __shared__ float t[64][65];
  const int k0 = blockIdx.x * 64, n0 = blockIdx.y * 64;
  const int tid = threadIdx.x;
  const int rr = tid >> 4, c4 = (tid & 15) * 4;
#pragma unroll
  for (int q = 0; q < 4; ++q) {
    int row = q * 16 + rr;
    const float4 v = *reinterpret_cast<const float4*>(W + (size_t)(k0 + row) * 256 + n0 + c4);
    t[row][c4 + 0] = v.x; t[row][c4 + 1] = v.y; t[row][c4 + 2] = v.z; t[row][c4 + 3] = v.w;
  }
  __syncthreads();
#pragma unroll
  for (int q = 0; q < 4; ++q) {
    int n = q * 16 + rr;
    ushort4 oh, ol;
    float w0 = t[c4 + 0][n], w1 = t[c4 + 1][n], w2 = t[c4 + 2][n], w3 = t[c4 + 3][n];
    oh.x = f2bf(w0); ol.x = f2bf(w0 - bf2f(oh.x));
    oh.y = f2bf(w1); ol.y = f2bf(w1 - bf2f(oh.y));
    oh.z = f2bf(w2); ol.z = f2bf(w2 - bf2f(oh.z));
    oh.w = f2bf(w3); ol.w = f2bf(w3 - bf2f(oh.w));
    *reinterpret_cast<ushort4*>(Wt_hi + (size_t)(n0 + n) * K + k0 + c4) = oh;
    *reinterpret_cast<ushort4*>(Wt_lo + (size_t)(n0 + n) * K + k0 + c4) = ol;
  }
}

// ---------------- CSR build ----------------
__global__ void count_rows_k(const int* __restrict__ row, int* __restrict__ cnt, int E) {
  int i = blockIdx.x * blockDim.x + threadIdx.x;
  if (i < E) atomicAdd(&cnt[row[i]], 1);
}

__global__ void scan_k(const int* __restrict__ cnt, int* __restrict__ row_ptr, int n) {
  __shared__ int sums[1024];
  int t = threadIdx.x;
  int chunk = (n + 1023) >> 10;
  int start = t * chunk;
  int end = min(start + chunk, n);
  int s = 0;
  for (int i = start; i < end; ++i) s += cnt[i];
  sums[t] = s;
  __syncthreads();
  for (int off = 1; off < 1024; off <<= 1) {
    int v = (t >= off) ? sums[t - off] : 0;
    __syncthreads();
    sums[t] += v;
    __syncthreads();
  }
  int base = (t == 0) ? 0 : sums[t - 1];
  for (int i = start; i < end; ++i) { row_ptr[i] = base; base += cnt[i]; }
  if (t == 1023) row_ptr[n] = sums[1023];
}

__global__ void scatter_k(const int* __restrict__ row, const int* __restrict__ col,
                          const float* __restrict__ val, int* __restrict__ cursor,
                          int2* __restrict__ cv, int E) {
  int i = blockIdx.x * blockDim.x + threadIdx.x;
  if (i < E) {
    int pos = atomicAdd(&cursor[row[i]], 1);
    cv[pos] = make_int2(col[i], __float_as_int(val[i]));
  }
}

__global__ void flag_k(const int* __restrict__ ids, unsigned char* __restrict__ flag, int B) {
  int i = blockIdx.x * blockDim.x + threadIdx.x;
  if (i < B) flag[ids[i]] = 1;
}

// ---------------- SpMM: f32 src/dst, CSR, one wave per row ----------------
__global__ __launch_bounds__(256) void spmm_k(
    const int* __restrict__ row_ptr, const int2* __restrict__ cv,
    const float* __restrict__ src, float* __restrict__ dst,
    const float* __restrict__ bias, int do_leaky,
    const unsigned char* __restrict__ flag, int n)
{
  int r = (blockIdx.x << 2) + (threadIdx.x >> 6);
  if (r >= n) return;
  if (flag && !flag[r]) return;
  const int lane = threadIdx.x & 63;
  const int c0 = lane << 2;
  int e0 = row_ptr[r], e1 = row_ptr[r + 1];
  float a0 = 0.f, a1 = 0.f, a2 = 0.f, a3 = 0.f;
  int e = e0;
  for (; e + 1 < e1; e += 2) {
    int2 p = cv[e];
    int2 q = cv[e + 1];
    float v = __int_as_float(p.y);
    float w = __int_as_float(q.y);
    const float4 x = *reinterpret_cast<const float4*>(src + (size_t)p.x * D_DIM + c0);
    const float4 y = *reinterpret_cast<const float4*>(src + (size_t)q.x * D_DIM + c0);
    a0 = fmaf(v, x.x, a0); a1 = fmaf(v, x.y, a1);
    a2 = fmaf(v, x.z, a2); a3 = fmaf(v, x.w, a3);
    a0 = fmaf(w, y.x, a0); a1 = fmaf(w, y.y, a1);
    a2 = fmaf(w, y.z, a2); a3 = fmaf(w, y.w, a3);
  }
  for (; e < e1; ++e) {
    int2 p = cv[e];
    float v = __int_as_float(p.y);
    const float4 x = *reinterpret_cast<const float4*>(src + (size_t)p.x * D_DIM + c0);
    a0 = fmaf(v, x.x, a0); a1 = fmaf(v, x.y, a1);
    a2 = fmaf(v, x.z, a2); a3 = fmaf(v, x.w, a3);
  }
  if (bias) {
    const float4 b = *reinterpret_cast<const float4*>(bias + c0);
    a0 += b.x; a1 += b.y; a2 += b.z; a3 += b.w;
  }
  if (do_leaky) {
    a0 = a0 > 0.f ? a0 : 0.01f * a0;
    a1 = a1 > 0.f ? a1 : 0.01f * a1;
    a2 = a2 > 0.f ? a2 : 0.01f * a2;
    a3 = a3 > 0.f ? a3 : 0.01f * a3;
  }
  *reinterpret_cast<float4*>(dst + (size_t)r * D_DIM + c0) =
      make_float4(a0, a1, a2, a3);
}

// ---------------- MFMA GEMM, split-precision bf16 (3-term) ----------------
// C[M,256] = epilogue(A[M,K] @ W + b), A fp32 split in registers to
// a_hi + a_lo; W pre-split to Wt_hi/Wt_lo [256][K]. acc gets
// ah@bh + al@bh + ah@bl  (al@bl dropped, ~2^-16 relative) => ~fp32 accuracy.
// MODE 0: C = A@W (+bias)      MODE 1: C = leaky(A@W + bias)
// MODE 2: g = sigmoid(A@W+bias); C = g*nxt[row] + (1-g)*hin[rowidx?rowidx[row]:row]
template<int KT, int MODE>
__global__ __launch_bounds__(256, 2) void mm_k(
    const float* __restrict__ Aptr,
    const unsigned short* __restrict__ Wt_hi,
    const unsigned short* __restrict__ Wt_lo,
    const float* __restrict__ bias,
    float* __restrict__ C, int ldc, int ccol0, int M,
    const int* __restrict__ rowidx,
    const float* __restrict__ nxt, const float* __restrict__ hin)
{
  const int tid = threadIdx.x;
  const int wid = tid >> 6, lane = tid & 63;
  const int wm = wid & 1, wn = wid >> 1;       // 2 (M) x 2 (N) waves
  const int bm = blockIdx.x * 64;
  const int l15 = lane & 15, lk = lane >> 4;   // k-group 0..3

  int mrow[2];
  const float* arow[2];
#pragma unroll
  for (int mi = 0; mi < 2; ++mi) {
    int m = bm + wm * 32 + mi * 16 + l15;
    mrow[mi] = m;
    int sr = (m < M) ? (rowidx ? rowidx[m] : m) : 0;
    arow[mi] = Aptr + (size_t)sr * KT;
  }
  const size_t woff = (size_t)(wn * 128 + l15) * KT;

  f32x4 acc[2][8] = {};
  for (int k0 = 0; k0 < KT; k0 += 32) {
    const int kk = k0 + lk * 8;
    bf16x8 ah[2], al[2];
#pragma unroll
    for (int mi = 0; mi < 2; ++mi) {
      bf16x8 th = {0, 0, 0, 0, 0, 0, 0, 0};
      bf16x8 tl = {0, 0, 0, 0, 0, 0, 0, 0};
      if (mrow[mi] < M) {
        const float* p = arow[mi] + kk;
        const float4 x = *reinterpret_cast<const float4*>(p);
        const float4 y = *reinterpret_cast<const float4*>(p + 4);
#define SPLIT_A(i, val) { unsigned short h_ = f2bf(val); th[i] = (short)h_; \
                          tl[i] = (short)f2bf((val) - bf2f(h_)); }
        SPLIT_A(0, x.x) SPLIT_A(1, x.y) SPLIT_A(2, x.z) SPLIT_A(3, x.w)
        SPLIT_A(4, y.x) SPLIT_A(5, y.y) SPLIT_A(6, y.z) SPLIT_A(7, y.w)
#undef SPLIT_A
      }
      ah[mi] = th; al[mi] = tl;
    }
#pragma unroll
    for (int f = 0; f < 8; ++f) {
      const size_t boff = woff + (size_t)f * 16 * KT + kk;
      const bf16x8 bh = *reinterpret_cast<const bf16x8*>(Wt_hi + boff);
      const bf16x8 bl = *reinterpret_cast<const bf16x8*>(Wt_lo + boff);
#pragma unroll
      for (int mi = 0; mi < 2; ++mi) {
        acc[mi][f] = __builtin_amdgcn_mfma_f32_16x16x32_bf16(ah[mi], bh, acc[mi][f], 0, 0, 0);
        acc[mi][f] = __builtin_amdgcn_mfma_f32_16x16x32_bf16(al[mi], bh, acc[mi][f], 0, 0, 0);
        acc[mi][f] = __builtin_amdgcn_mfma_f32_16x16x32_bf16(ah[mi], bl, acc[mi][f], 0, 0, 0);
      }
    }
  }

  __syncthreads();   // in-place safety: all A reads in block done before writes

#pragma unroll
  for (int mi = 0; mi < 2; ++mi) {
    const int rbase = bm + wm * 32 + mi * 16 + lk * 4;
    int hsrc[4];
    if (MODE == 2) {
#pragma unroll
      for (int r = 0; r < 4; ++r) {
        const int row = rbase + r;
        hsrc[r] = (rowidx && row < M) ? rowidx[row] : row;
      }
    }
#pragma unroll
    for (int f = 0; f < 8; ++f) {
      const int col = wn * 128 + f * 16 + l15;
      const float bc = bias ? bias[col] : 0.f;
#pragma unroll
      for (int r = 0; r < 4; ++r) {
        const int row = rbase + r;
        if (row >= M) continue;
        float v = acc[mi][f][r] + bc;
        if (MODE == 1) v = v > 0.f ? v : 0.01f * v;
        if (MODE == 2) {
          const float g = 1.f / (1.f + __expf(-v));
          const float nv = nxt[(size_t)row * D_DIM + col];
          const float hv = hin[(size_t)hsrc[r] * D_DIM + col];
          v = g * nv + (1.f - g) * hv;
        }
        C[(size_t)row * ldc + ccol0 + col] = v;
      }
    }
  }
}

// ---------------- row gather (f32 src -> f32 out columns) ----------------
__global__ __launch_bounds__(256) void gather_k(const float* __restrict__ src,
                                                const int* __restrict__ ids,
                                                float* __restrict__ dst, int ccol0, int B)
{
  int i = (blockIdx.x << 2) + (threadIdx.x >> 6);
  if (i >= B) return;
  const int lane = threadIdx.x & 63;
  const int c0 = lane << 2;
  const float4 v = *reinterpret_cast<const float4*>(src + (size_t)ids[i] * D_DIM + c0);
  *reinterpret_cast<float4*>(dst + (size_t)i * 1024 + ccol0 + c0) = v;
}

// ---------------- launch ----------------
extern "C" void kernel_launch(void* const* d_in, const int* in_sizes, int n_in,
                              void* d_out, int out_size, void* d_ws, size_t ws_size,
                              hipStream_t stream)
{
  const float* ent_lit = (const float*)d_in[0];
  const float* rel_lit = (const float*)d_in[1];
  const float* attr_lit = (const float*)d_in[2];
  const float* ent_val = (const float*)d_in[3];
  const float* rel_val = (const float*)d_in[4];
  const float* attr_val = (const float*)d_in[5];
  const float* W_ent = (const float*)d_in[6];
  const float* b_ent = (const float*)d_in[7];
  const float* W_rel = (const float*)d_in[8];
  const float* b_rel = (const float*)d_in[9];
  const float* W_attr = (const float*)d_in[10];
  const float* b_attr = (const float*)d_in[11];
  const float* W_x = (const float*)d_in[12];
  const float* b_x = (const float*)d_in[13];
  const float* W_lit = (const float*)d_in[14];
  const float* b_lit = (const float*)d_in[15];
  const float* W_gate = (const float*)d_in[16];
  const float* b_gate = (const float*)d_in[17];
  const int* ent_row = (const int*)d_in[18];
  const int* ent_col = (const int*)d_in[19];
  const int* rel_row = (const int*)d_in[20];
  const int* rel_col = (const int*)d_in[21];
  const int* attr_row = (const int*)d_in[22];
  const int* attr_col = (const int*)d_in[23];
  const int* ent_ids = (const int*)d_in[24];
  float* out = (float*)d_out;

  char* p = (char*)d_ws;
  const size_t bufsz = alignup((size_t)N_NODES * D_DIM * 4);
  const size_t wsz_f = alignup((size_t)F_DIM * D_DIM * 2);
  const size_t wsz_d = alignup((size_t)D_DIM * D_DIM * 2);
  float* B0 = (float*)p; p += bufsz;
  float* B1 = (float*)p; p += bufsz;
  float* P  = (float*)p; p += alignup((size_t)B_IDS * D_DIM * 4);
  unsigned short* Wh_ent = (unsigned short*)p; p += wsz_f;
  unsigned short* Wl_ent = (unsigned short*)p; p += wsz_f;
  unsigned short* Wh_rel = (unsigned short*)p; p += wsz_f;
  unsigned short* Wl_rel = (unsigned short*)p; p += wsz_f;
  unsigned short* Wh_attr = (unsigned short*)p; p += wsz_f;
  unsigned short* Wl_attr = (unsigned short*)p; p += wsz_f;
  unsigned short* Wh_lit = (unsigned short*)p; p += wsz_f;
  unsigned short* Wl_lit = (unsigned short*)p; p += wsz_f;
  unsigned short* Wh_x = (unsigned short*)p; p += wsz_d;
  unsigned short* Wl_x = (unsigned short*)p; p += wsz_d;
  unsigned short* Wh_gate = (unsigned short*)p; p += wsz_d;
  unsigned short* Wl_gate = (unsigned short*)p; p += wsz_d;
  int* row_ptr = (int*)p; p += alignup((size_t)(N_NODES + 1) * 4);
  int* cursor = (int*)p; p += alignup((size_t)N_NODES * 4);
  unsigned char* flags = (unsigned char*)p; p += alignup((size_t)N_NODES);
  int2* cv = (int2*)p; p += alignup((size_t)N_EDGES * 8);
  if ((size_t)(p - (char*)d_ws) > ws_size) return;

  dim3 blk(256);
  dim3 g_edges((N_EDGES + 255) / 256);
  dim3 g_spmm((N_NODES + 3) / 4);
  dim3 g_gather((B_IDS + 3) / 4);
  dim3 g_mm_big((N_NODES + 63) / 64);
  dim3 g_mm_ids(B_IDS / 64);

  // weights -> bf16 hi/lo transposed
  tr_k<<<dim3(F_DIM / 64, 4), blk, 0, stream>>>(W_ent, Wh_ent, Wl_ent, F_DIM);
  tr_k<<<dim3(F_DIM / 64, 4), blk, 0, stream>>>(W_rel, Wh_rel, Wl_rel, F_DIM);
  tr_k<<<dim3(F_DIM / 64, 4), blk, 0, stream>>>(W_attr, Wh_attr, Wl_attr, F_DIM);
  tr_k<<<dim3(F_DIM / 64, 4), blk, 0, stream>>>(W_lit, Wh_lit, Wl_lit, F_DIM);
  tr_k<<<dim3(D_DIM / 64, 4), blk, 0, stream>>>(W_x, Wh_x, Wl_x, D_DIM);
  tr_k<<<dim3(D_DIM / 64, 4), blk, 0, stream>>>(W_gate, Wh_gate, Wl_gate, D_DIM);

  // flags for row restriction (rows observed via ent_ids)
  hipMemsetAsync(flags, 0, N_NODES, stream);
  flag_k<<<dim3(B_IDS / 256), blk, 0, stream>>>(ent_ids, flags, B_IDS);

  auto build_csr = [&](const int* row, const int* col, const float* val) {
    hipMemsetAsync(cursor, 0, N_NODES * sizeof(int), stream);
    count_rows_k<<<g_edges, blk, 0, stream>>>(row, cursor, N_EDGES);
    scan_k<<<1, 1024, 0, stream>>>(cursor, row_ptr, N_NODES);
    hipMemcpyAsync(cursor, row_ptr, N_NODES * sizeof(int), hipMemcpyDeviceToDevice, stream);
    scatter_k<<<g_edges, blk, 0, stream>>>(row, col, val, cursor, cv, N_EDGES);
  };

  // ----- rel branch -> out[:,512:768]
  build_csr(rel_row, rel_col, rel_val);
  mm_k<F_DIM, 0><<<g_mm_big, blk, 0, stream>>>(rel_lit, Wh_rel, Wl_rel, nullptr, B0, D_DIM, 0,
                                               N_NODES, nullptr, nullptr, nullptr);
  spmm_k<<<g_spmm, blk, 0, stream>>>(row_ptr, cv, B0, B1, b_rel, 1, flags, N_NODES);
  gather_k<<<g_gather, blk, 0, stream>>>(B1, ent_ids, out, 512, B_IDS);

  // ----- attr branch -> out[:,768:1024]
  build_csr(attr_row, attr_col, attr_val);
  mm_k<F_DIM, 0><<<g_mm_big, blk, 0, stream>>>(attr_lit, Wh_attr, Wl_attr, nullptr, B0, D_DIM, 0,
                                               N_NODES, nullptr, nullptr, nullptr);
  spmm_k<<<g_spmm, blk, 0, stream>>>(row_ptr, cv, B0, B1, b_attr, 1, flags, N_NODES);
  gather_k<<<g_gather, blk, 0, stream>>>(B1, ent_ids, out, 768, B_IDS);

  // ----- ent literals -> out[:,0:256]
  mm_k<F_DIM, 0><<<g_mm_ids, blk, 0, stream>>>(ent_lit, Wh_lit, Wl_lit, b_lit, out, 1024, 0,
                                               B_IDS, ent_ids, nullptr, nullptr);

  // ----- ent n-hop -----
  build_csr(ent_row, ent_col, ent_val);
  mm_k<F_DIM, 0><<<g_mm_big, blk, 0, stream>>>(ent_lit, Wh_ent, Wl_ent, nullptr, B0, D_DIM, 0,
                                               N_NODES, nullptr, nullptr, nullptr);
  spmm_k<<<g_spmm, blk, 0, stream>>>(row_ptr, cv, B0, B1, b_ent, 1, nullptr, N_NODES); // h1=B1
  // hop 2 (all rows; nxt and h2 computed in place)
  spmm_k<<<g_spmm, blk, 0, stream>>>(row_ptr, cv, B1, B0, nullptr, 0, nullptr, N_NODES); // s2=B0
  mm_k<D_DIM, 1><<<g_mm_big, blk, 0, stream>>>(B0, Wh_x, Wl_x, b_x, B0, D_DIM, 0,
                                               N_NODES, nullptr, nullptr, nullptr);  // nxt2=B0 (in place)
  mm_k<D_DIM, 2><<<g_mm_big, blk, 0, stream>>>(B1, Wh_gate, Wl_gate, b_gate, B1, D_DIM, 0,
                                               N_NODES, nullptr, B0, B1);            // h2=B1 (in place)
  // hop 3 (only rows observed via ent_ids)
  spmm_k<<<g_spmm, blk, 0, stream>>>(row_ptr, cv, B1, B0, nullptr, 0, flags, N_NODES); // s3=B0
  mm_k<D_DIM, 1><<<g_mm_ids, blk, 0, stream>>>(B0, Wh_x, Wl_x, b_x, P, D_DIM, 0,
                                               B_IDS, ent_ids, nullptr, nullptr);    // nxt3 by position
  mm_k<D_DIM, 2><<<g_mm_ids, blk, 0, stream>>>(B1, Wh_gate, Wl_gate, b_gate, out, 1024, 256,
                                               B_IDS, ent_ids, P, B1);               // -> out[:,256:512]
}

// Round 6
// 2195.882 us; speedup vs baseline: 1.5873x; 1.2665x over previous
//
#include <hip/hip_runtime.h>
#include <math.h>

#define N_NODES 50000
#define N_EDGES 1600000
#define F_DIM 1024
#define D_DIM 256
#define B_IDS 16384

typedef __attribute__((ext_vector_type(8))) short bf16x8;
typedef __attribute__((ext_vector_type(4))) float f32x4;

static inline size_t alignup(size_t x) { return (x + 255) & ~(size_t)255; }

__device__ inline unsigned short f2bf(float f) {
  unsigned u = __float_as_uint(f);
  u += 0x7fffu + ((u >> 16) & 1u);   // RNE (inputs are finite)
  return (unsigned short)(u >> 16);
}
__device__ inline float bf2f(unsigned short u) {
  return __uint_as_float(((unsigned)u) << 16);
}

__device__ inline void glds16(const void* g, void* l) {
  __builtin_amdgcn_global_load_lds(
      (const __attribute__((address_space(1))) void*)g,
      (__attribute__((address_space(3))) void*)l, 16, 0, 0);
}

// ---- fused weight transpose + bf16 hi/lo split for all 6 weights ----
struct TrArgs {
  const float* W[6];
  unsigned short* Wh[6];
  unsigned short* Wl[6];
  int K[6];
};

__global__ __launch_bounds__(256) void tr_all_k(TrArgs a) {
  const int z = blockIdx.z;
  const int K = a.K[z];
  if (blockIdx.x * 64 >= K) return;
  const float* W = a.W[z];
  unsigned short* Wt_hi = a.Wh[z];
  unsigned short* Wt_lo = a.Wl[z];
  __shared__ float t[64][65];
  const int k0 = blockIdx.x * 64, n0 = blockIdx.y * 64;
  const int tid = threadIdx.x;
  const int rr = tid >> 4, c4 = (tid & 15) * 4;
#pragma unroll
  for (int q = 0; q < 4; ++q) {
    int row = q * 16 + rr;
    const float4 v = *reinterpret_cast<const float4*>(W + (size_t)(k0 + row) * 256 + n0 + c4);
    t[row][c4 + 0] = v.x; t[row][c4 + 1] = v.y; t[row][c4 + 2] = v.z; t[row][c4 + 3] = v.w;
  }
  __syncthreads();
#pragma unroll
  for (int q = 0; q < 4; ++q) {
    int n = q * 16 + rr;
    ushort4 oh, ol;
    float w0 = t[c4 + 0][n], w1 = t[c4 + 1][n], w2 = t[c4 + 2][n], w3 = t[c4 + 3][n];
    oh.x = f2bf(w0); ol.x = f2bf(w0 - bf2f(oh.x));
    oh.y = f2bf(w1); ol.y = f2bf(w1 - bf2f(oh.y));
    oh.z = f2bf(w2); ol.z = f2bf(w2 - bf2f(oh.z));
    oh.w = f2bf(w3); ol.w = f2bf(w3 - bf2f(oh.w));
    *reinterpret_cast<ushort4*>(Wt_hi + (size_t)(n0 + n) * K + k0 + c4) = oh;
    *reinterpret_cast<ushort4*>(Wt_lo + (size_t)(n0 + n) * K + k0 + c4) = ol;
  }
}

// ---------------- fused CSR build (3 graphs) ----------------
__global__ void count3_k(const int* __restrict__ r0, const int* __restrict__ r1,
                         const int* __restrict__ r2, int* __restrict__ cnt, int E) {
  int i = blockIdx.x * blockDim.x + threadIdx.x;
  if (i < E) atomicAdd(&cnt[r0[i]], 1);
  else if (i < 2 * E) atomicAdd(&cnt[N_NODES + r1[i - E]], 1);
  else if (i < 3 * E) atomicAdd(&cnt[2 * N_NODES + r2[i - 2 * E]], 1);
}

// one block per graph; writes row_ptr AND leaves cnt[] holding start offsets (cursor)
__global__ void scan3_k(int* __restrict__ cnt, int* __restrict__ row_ptr, int n) {
  __shared__ int sums[1024];
  const int g = blockIdx.x;
  int* c = cnt + (size_t)g * n;
  int* rp = row_ptr + (size_t)g * (n + 1);
  int t = threadIdx.x;
  int chunk = (n + 1023) >> 10;
  int start = t * chunk;
  int end = min(start + chunk, n);
  int s = 0;
  for (int i = start; i < end; ++i) s += c[i];
  sums[t] = s;
  __syncthreads();
  for (int off = 1; off < 1024; off <<= 1) {
    int v = (t >= off) ? sums[t - off] : 0;
    __syncthreads();
    sums[t] += v;
    __syncthreads();
  }
  int base = (t == 0) ? 0 : sums[t - 1];
  for (int i = start; i < end; ++i) {
    int ci = c[i];
    rp[i] = base;
    c[i] = base;      // cursor
    base += ci;
  }
  if (t == 1023) rp[n] = sums[1023];
}

__global__ void scatter3_k(const int* __restrict__ r0, const int* __restrict__ c0, const float* __restrict__ v0,
                           const int* __restrict__ r1, const int* __restrict__ c1, const float* __restrict__ v1,
                           const int* __restrict__ r2, const int* __restrict__ c2, const float* __restrict__ v2,
                           int* __restrict__ cursor, int2* __restrict__ cv, int E) {
  int i = blockIdx.x * blockDim.x + threadIdx.x;
  int g, j;
  const int *r, *c;
  const float* v;
  if (i < E) { g = 0; j = i; r = r0; c = c0; v = v0; }
  else if (i < 2 * E) { g = 1; j = i - E; r = r1; c = c1; v = v1; }
  else if (i < 3 * E) { g = 2; j = i - 2 * E; r = r2; c = c2; v = v2; }
  else return;
  int pos = atomicAdd(&cursor[g * N_NODES + r[j]], 1);
  cv[(size_t)g * E + pos] = make_int2(c[j], __float_as_int(v[j]));
}

__global__ void flag_k(const int* __restrict__ ids, unsigned char* __restrict__ flag, int B) {
  int i = blockIdx.x * blockDim.x + threadIdx.x;
  if (i < B) flag[ids[i]] = 1;
}

// ---------------- SpMM: f32 src/dst, CSR, one wave per row ----------------
__global__ __launch_bounds__(256) void spmm_k(
    const int* __restrict__ row_ptr, const int2* __restrict__ cv,
    const float* __restrict__ src, float* __restrict__ dst,
    const float* __restrict__ bias, int do_leaky,
    const unsigned char* __restrict__ flag, int n)
{
  int r = (blockIdx.x << 2) + (threadIdx.x >> 6);
  if (r >= n) return;
  if (flag && !flag[r]) return;
  const int lane = threadIdx.x & 63;
  const int c0 = lane << 2;
  int e0 = row_ptr[r], e1 = row_ptr[r + 1];
  float a0 = 0.f, a1 = 0.f, a2 = 0.f, a3 = 0.f;
  int e = e0;
  for (; e + 1 < e1; e += 2) {
    int2 p = cv[e];
    int2 q = cv[e + 1];
    float v = __int_as_float(p.y);
    float w = __int_as_float(q.y);
    const float4 x = *reinterpret_cast<const float4*>(src + (size_t)p.x * D_DIM + c0);
    const float4 y = *reinterpret_cast<const float4*>(src + (size_t)q.x * D_DIM + c0);
    a0 = fmaf(v, x.x, a0); a1 = fmaf(v, x.y, a1);
    a2 = fmaf(v, x.z, a2); a3 = fmaf(v, x.w, a3);
    a0 = fmaf(w, y.x, a0); a1 = fmaf(w, y.y, a1);
    a2 = fmaf(w, y.z, a2); a3 = fmaf(w, y.w, a3);
  }
  for (; e < e1; ++e) {
    int2 p = cv[e];
    float v = __int_as_float(p.y);
    const float4 x = *reinterpret_cast<const float4*>(src + (size_t)p.x * D_DIM + c0);
    a0 = fmaf(v, x.x, a0); a1 = fmaf(v, x.y, a1);
    a2 = fmaf(v, x.z, a2); a3 = fmaf(v, x.w, a3);
  }
  if (bias) {
    const float4 b = *reinterpret_cast<const float4*>(bias + c0);
    a0 += b.x; a1 += b.y; a2 += b.z; a3 += b.w;
  }
  if (do_leaky) {
    a0 = a0 > 0.f ? a0 : 0.01f * a0;
    a1 = a1 > 0.f ? a1 : 0.01f * a1;
    a2 = a2 > 0.f ? a2 : 0.01f * a2;
    a3 = a3 > 0.f ? a3 : 0.01f * a3;
  }
  *reinterpret_cast<float4*>(dst + (size_t)r * D_DIM + c0) =
      make_float4(a0, a1, a2, a3);
}

// ---------------- MFMA GEMM, split-precision bf16 (3-term), LDS B-staging ----
// C[M,256] = epilogue(A[M,K] @ W + b). A fp32, split to hi/lo in registers.
// W pre-split to Wt_hi/Wt_lo [256][K] bf16. Per 32-K chunk the block stages
// hi+lo tiles (32 KB) into LDS with global_load_lds (width 16). LDS dest is
// linear (glds requirement); the k-segment permutation j=(lk+(n>>1))&3 is
// applied on the GLOBAL source when staging and on the ds_read offset when
// reading (both-sides rule), giving a 2-way (free) bank pattern.
// MODE 0: C = A@W (+bias)      MODE 1: C = leaky(A@W + bias)
// MODE 2: g = sigmoid(A@W+bias); C = g*nxt[row] + (1-g)*hin[rowidx?rowidx[row]:row]
template<int KT, int MODE>
__global__ __launch_bounds__(256, 2) void mm_k(
    const float* __restrict__ Aptr,
    const unsigned short* __restrict__ Wt_hi,
    const unsigned short* __restrict__ Wt_lo,
    const float* __restrict__ bias,
    float* __restrict__ C, int ldc, int ccol0, int M,
    const int* __restrict__ rowidx,
    const float* __restrict__ nxt, const float* __restrict__ hin)
{
  __shared__ __align__(16) unsigned char smem[32768];  // hi: [0,16K), lo: [16K,32K)
  const int tid = threadIdx.x;
  const int wid = tid >> 6, lane = tid & 63;
  const int wm = wid & 1, wn = wid >> 1;       // 2 (M) x 2 (N) waves
  const int bm = blockIdx.x * 64;
  const int l15 = lane & 15, lk = lane >> 4;   // k-group 0..3

  int mrow[2];
  const float* arow[2];
#pragma unroll
  for (int mi = 0; mi < 2; ++mi) {
    int m = bm + wm * 32 + mi * 16 + l15;
    mrow[mi] = m;
    int sr = (m < M) ? (rowidx ? rowidx[m] : m) : 0;
    arow[mi] = Aptr + (size_t)sr * KT;
  }

  // staging lane constants: row-in-tile and permuted k-segment
  const int st_r = lane >> 2;                               // 0..15 within 16-row group
  const int st_seg = ((lane & 3) - ((lane >> 3) & 3)) & 3;  // pre-swizzled k-seg

  f32x4 acc[2][8] = {};
  for (int kc = 0; kc < KT / 32; ++kc) {
    const int kk = kc * 32;
    __syncthreads();   // previous chunk's reads complete before overwrite
#pragma unroll
    for (int i = 0; i < 4; ++i) {
      const size_t goff = (size_t)(wid * 64 + i * 16 + st_r) * KT + kk + st_seg * 8;
      const unsigned lbase = wid * 4096 + i * 1024;
      glds16(Wt_hi + goff, smem + lbase);
      glds16(Wt_lo + goff, smem + 16384 + lbase);
    }
    // A fragments (overlap with staging latency)
    const int ka = kk + lk * 8;
    bf16x8 ah[2], al[2];
#pragma unroll
    for (int mi = 0; mi < 2; ++mi) {
      bf16x8 th = {0, 0, 0, 0, 0, 0, 0, 0};
      bf16x8 tl = {0, 0, 0, 0, 0, 0, 0, 0};
      if (mrow[mi] < M) {
        const float* p = arow[mi] + ka;
        const float4 x = *reinterpret_cast<const float4*>(p);
        const float4 y = *reinterpret_cast<const float4*>(p + 4);
#define SPLIT_A(i, val) { unsigned short h_ = f2bf(val); th[i] = (short)h_; \
                          tl[i] = (short)f2bf((val) - bf2f(h_)); }
        SPLIT_A(0, x.x) SPLIT_A(1, x.y) SPLIT_A(2, x.z) SPLIT_A(3, x.w)
        SPLIT_A(4, y.x) SPLIT_A(5, y.y) SPLIT_A(6, y.z) SPLIT_A(7, y.w)
#undef SPLIT_A
      }
      ah[mi] = th; al[mi] = tl;
    }
    __syncthreads();   // staging drained (vmcnt(0) before barrier)
#pragma unroll
    for (int f = 0; f < 8; ++f) {
      const int n = wn * 128 + f * 16 + l15;
      const int boff = n * 64 + (((lk + (l15 >> 1)) & 3) << 4);
      const bf16x8 bh = *reinterpret_cast<const bf16x8*>(smem + boff);
      const bf16x8 bl = *reinterpret_cast<const bf16x8*>(smem + 16384 + boff);
#pragma unroll
      for (int mi = 0; mi < 2; ++mi) {
        acc[mi][f] = __builtin_amdgcn_mfma_f32_16x16x32_bf16(ah[mi], bh, acc[mi][f], 0, 0, 0);
        acc[mi][f] = __builtin_amdgcn_mfma_f32_16x16x32_bf16(al[mi], bh, acc[mi][f], 0, 0, 0);
        acc[mi][f] = __builtin_amdgcn_mfma_f32_16x16x32_bf16(ah[mi], bl, acc[mi][f], 0, 0, 0);
      }
    }
  }

  __syncthreads();   // in-place safety: all A reads in block done before writes

#pragma unroll
  for (int mi = 0; mi < 2; ++mi) {
    const int rbase = bm + wm * 32 + mi * 16 + lk * 4;
    int hsrc[4];
    if (MODE == 2) {
#pragma unroll
      for (int r = 0; r < 4; ++r) {
        const int row = rbase + r;
        hsrc[r] = (rowidx && row < M) ? rowidx[row] : row;
      }
    }
#pragma unroll
    for (int f = 0; f < 8; ++f) {
      const int col = wn * 128 + f * 16 + l15;
      const float bc = bias ? bias[col] : 0.f;
#pragma unroll
      for (int r = 0; r < 4; ++r) {
        const int row = rbase + r;
        if (row >= M) continue;
        float v = acc[mi][f][r] + bc;
        if (MODE == 1) v = v > 0.f ? v : 0.01f * v;
        if (MODE == 2) {
          const float g = 1.f / (1.f + __expf(-v));
          const float nv = nxt[(size_t)row * D_DIM + col];
          const float hv = hin[(size_t)hsrc[r] * D_DIM + col];
          v = g * nv + (1.f - g) * hv;
        }
        C[(size_t)row * ldc + ccol0 + col] = v;
      }
    }
  }
}

// ---------------- row gather (f32 src -> f32 out columns) ----------------
__global__ __launch_bounds__(256) void gather_k(const float* __restrict__ src,
                                                const int* __restrict__ ids,
                                                float* __restrict__ dst, int ccol0, int B)
{
  int i = (blockIdx.x << 2) + (threadIdx.x >> 6);
  if (i >= B) return;
  const int lane = threadIdx.x & 63;
  const int c0 = lane << 2;
  const float4 v = *reinterpret_cast<const float4*>(src + (size_t)ids[i] * D_DIM + c0);
  *reinterpret_cast<float4*>(dst + (size_t)i * 1024 + ccol0 + c0) = v;
}

// ---------------- launch ----------------
extern "C" void kernel_launch(void* const* d_in, const int* in_sizes, int n_in,
                              void* d_out, int out_size, void* d_ws, size_t ws_size,
                              hipStream_t stream)
{
  const float* ent_lit = (const float*)d_in[0];
  const float* rel_lit = (const float*)d_in[1];
  const float* attr_lit = (const float*)d_in[2];
  const float* ent_val = (const float*)d_in[3];
  const float* rel_val = (const float*)d_in[4];
  const float* attr_val = (const float*)d_in[5];
  const float* W_ent = (const float*)d_in[6];
  const float* b_ent = (const float*)d_in[7];
  const float* W_rel = (const float*)d_in[8];
  const float* b_rel = (const float*)d_in[9];
  const float* W_attr = (const float*)d_in[10];
  const float* b_attr = (const float*)d_in[11];
  const float* W_x = (const float*)d_in[12];
  const float* b_x = (const float*)d_in[13];
  const float* W_lit = (const float*)d_in[14];
  const float* b_lit = (const float*)d_in[15];
  const float* W_gate = (const float*)d_in[16];
  const float* b_gate = (const float*)d_in[17];
  const int* ent_row = (const int*)d_in[18];
  const int* ent_col = (const int*)d_in[19];
  const int* rel_row = (const int*)d_in[20];
  const int* rel_col = (const int*)d_in[21];
  const int* attr_row = (const int*)d_in[22];
  const int* attr_col = (const int*)d_in[23];
  const int* ent_ids = (const int*)d_in[24];
  float* out = (float*)d_out;

  char* p = (char*)d_ws;
  const size_t bufsz = alignup((size_t)N_NODES * D_DIM * 4);
  const size_t wsz_f = alignup((size_t)F_DIM * D_DIM * 2);
  const size_t wsz_d = alignup((size_t)D_DIM * D_DIM * 2);
  float* B0 = (float*)p; p += bufsz;
  float* B1 = (float*)p; p += bufsz;
  float* P  = (float*)p; p += alignup((size_t)B_IDS * D_DIM * 4);
  unsigned short* Wh_ent = (unsigned short*)p; p += wsz_f;
  unsigned short* Wl_ent = (unsigned short*)p; p += wsz_f;
  unsigned short* Wh_rel = (unsigned short*)p; p += wsz_f;
  unsigned short* Wl_rel = (unsigned short*)p; p += wsz_f;
  unsigned short* Wh_attr = (unsigned short*)p; p += wsz_f;
  unsigned short* Wl_attr = (unsigned short*)p; p += wsz_f;
  unsigned short* Wh_lit = (unsigned short*)p; p += wsz_f;
  unsigned short* Wl_lit = (unsigned short*)p; p += wsz_f;
  unsigned short* Wh_x = (unsigned short*)p; p += wsz_d;
  unsigned short* Wl_x = (unsigned short*)p; p += wsz_d;
  unsigned short* Wh_gate = (unsigned short*)p; p += wsz_d;
  unsigned short* Wl_gate = (unsigned short*)p; p += wsz_d;
  int* row_ptr3 = (int*)p; p += alignup((size_t)3 * (N_NODES + 1) * 4);
  int* cnt3 = (int*)p; p += alignup((size_t)3 * N_NODES * 4);   // doubles as cursor
  unsigned char* flags = (unsigned char*)p; p += alignup((size_t)N_NODES);
  int2* cv3 = (int2*)p; p += alignup((size_t)3 * N_EDGES * 8);
  if ((size_t)(p - (char*)d_ws) > ws_size) return;

  const int* rp_ent = row_ptr3;
  const int* rp_rel = row_ptr3 + (N_NODES + 1);
  const int* rp_attr = row_ptr3 + 2 * (N_NODES + 1);
  const int2* cv_ent = cv3;
  const int2* cv_rel = cv3 + (size_t)N_EDGES;
  const int2* cv_attr = cv3 + (size_t)2 * N_EDGES;

  dim3 blk(256);
  dim3 g_edges3((3 * N_EDGES + 255) / 256);
  dim3 g_spmm((N_NODES + 3) / 4);
  dim3 g_gather((B_IDS + 3) / 4);
  dim3 g_mm_big((N_NODES + 63) / 64);
  dim3 g_mm_ids(B_IDS / 64);

  // weights -> bf16 hi/lo transposed (one fused launch)
  TrArgs ta;
  ta.W[0] = W_ent;  ta.Wh[0] = Wh_ent;  ta.Wl[0] = Wl_ent;  ta.K[0] = F_DIM;
  ta.W[1] = W_rel;  ta.Wh[1] = Wh_rel;  ta.Wl[1] = Wl_rel;  ta.K[1] = F_DIM;
  ta.W[2] = W_attr; ta.Wh[2] = Wh_attr; ta.Wl[2] = Wl_attr; ta.K[2] = F_DIM;
  ta.W[3] = W_lit;  ta.Wh[3] = Wh_lit;  ta.Wl[3] = Wl_lit;  ta.K[3] = F_DIM;
  ta.W[4] = W_x;    ta.Wh[4] = Wh_x;    ta.Wl[4] = Wl_x;    ta.K[4] = D_DIM;
  ta.W[5] = W_gate; ta.Wh[5] = Wh_gate; ta.Wl[5] = Wl_gate; ta.K[5] = D_DIM;
  tr_all_k<<<dim3(F_DIM / 64, 4, 6), blk, 0, stream>>>(ta);

  // fused CSR build for ent/rel/attr
  hipMemsetAsync(cnt3, 0, (size_t)3 * N_NODES * sizeof(int), stream);
  count3_k<<<g_edges3, blk, 0, stream>>>(ent_row, rel_row, attr_row, cnt3, N_EDGES);
  scan3_k<<<dim3(3), dim3(1024), 0, stream>>>(cnt3, row_ptr3, N_NODES);
  scatter3_k<<<g_edges3, blk, 0, stream>>>(ent_row, ent_col, ent_val,
                                           rel_row, rel_col, rel_val,
                                           attr_row, attr_col, attr_val,
                                           cnt3, cv3, N_EDGES);

  // flags for row restriction (rows observed via ent_ids)
  hipMemsetAsync(flags, 0, N_NODES, stream);
  flag_k<<<dim3(B_IDS / 256), blk, 0, stream>>>(ent_ids, flags, B_IDS);

  // ----- rel branch -> out[:,512:768]
  mm_k<F_DIM, 0><<<g_mm_big, blk, 0, stream>>>(rel_lit, Wh_rel, Wl_rel, nullptr, B0, D_DIM, 0,
                                               N_NODES, nullptr, nullptr, nullptr);
  spmm_k<<<g_spmm, blk, 0, stream>>>(rp_rel, cv_rel, B0, B1, b_rel, 1, flags, N_NODES);
  gather_k<<<g_gather, blk, 0, stream>>>(B1, ent_ids, out, 512, B_IDS);

  // ----- attr branch -> out[:,768:1024]
  mm_k<F_DIM, 0><<<g_mm_big, blk, 0, stream>>>(attr_lit, Wh_attr, Wl_attr, nullptr, B0, D_DIM, 0,
                                               N_NODES, nullptr, nullptr, nullptr);
  spmm_k<<<g_spmm, blk, 0, stream>>>(rp_attr, cv_attr, B0, B1, b_attr, 1, flags, N_NODES);
  gather_k<<<g_gather, blk, 0, stream>>>(B1, ent_ids, out, 768, B_IDS);

  // ----- ent literals -> out[:,0:256]
  mm_k<F_DIM, 0><<<g_mm_ids, blk, 0, stream>>>(ent_lit, Wh_lit, Wl_lit, b_lit, out, 1024, 0,
                                               B_IDS, ent_ids, nullptr, nullptr);

  // ----- ent n-hop -----
  mm_k<F_DIM, 0><<<g_mm_big, blk, 0, stream>>>(ent_lit, Wh_ent, Wl_ent, nullptr, B0, D_DIM, 0,
                                               N_NODES, nullptr, nullptr, nullptr);
  spmm_k<<<g_spmm, blk, 0, stream>>>(rp_ent, cv_ent, B0, B1, b_ent, 1, nullptr, N_NODES); // h1=B1
  // hop 2 (all rows; nxt and h2 computed in place)
  spmm_k<<<g_spmm, blk, 0, stream>>>(rp_ent, cv_ent, B1, B0, nullptr, 0, nullptr, N_NODES); // s2=B0
  mm_k<D_DIM, 1><<<g_mm_big, blk, 0, stream>>>(B0, Wh_x, Wl_x, b_x, B0, D_DIM, 0,
                                               N_NODES, nullptr, nullptr, nullptr);  // nxt2=B0 (in place)
  mm_k<D_DIM, 2><<<g_mm_big, blk, 0, stream>>>(B1, Wh_gate, Wl_gate, b_gate, B1, D_DIM, 0,
                                               N_NODES, nullptr, B0, B1);            // h2=B1 (in place)
  // hop 3 (only rows observed via ent_ids)
  spmm_k<<<g_spmm, blk, 0, stream>>>(rp_ent, cv_ent, B1, B0, nullptr, 0, flags, N_NODES); // s3=B0
  mm_k<D_DIM, 1><<<g_mm_ids, blk, 0, stream>>>(B0, Wh_x, Wl_x, b_x, P, D_DIM, 0,
                                               B_IDS, ent_ids, nullptr, nullptr);    // nxt3 by position
  mm_k<D_DIM, 2><<<g_mm_ids, blk, 0, stream>>>(B1, Wh_gate, Wl_gate, b_gate, out, 1024, 256,
                                               B_IDS, ent_ids, P, B1);               // -> out[:,256:512]
}

// Round 7
// 1563.758 us; speedup vs baseline: 2.2289x; 1.4042x over previous
//
#include <hip/hip_runtime.h>
#include <math.h>

#define N_NODES 50000
#define N_EDGES 1600000
#define F_DIM 1024
#define D_DIM 256
#define B_IDS 16384

#define BROWS 1024            // rows per bucket
#define BKT 49                // buckets per graph (ceil(50000/1024))
#define NB3 (3 * BKT)         // 147
#define CHUNK 4096            // edges per partition block

typedef __attribute__((ext_vector_type(8))) short bf16x8;
typedef __attribute__((ext_vector_type(4))) float f32x4;

static inline size_t alignup(size_t x) { return (x + 255) & ~(size_t)255; }

__device__ inline unsigned short f2bf(float f) {
  unsigned u = __float_as_uint(f);
  u += 0x7fffu + ((u >> 16) & 1u);   // RNE (inputs are finite)
  return (unsigned short)(u >> 16);
}
__device__ inline float bf2f(unsigned short u) {
  return __uint_as_float(((unsigned)u) << 16);
}

__device__ inline void glds16(const void* g, void* l) {
  __builtin_amdgcn_global_load_lds(
      (const __attribute__((address_space(1))) void*)g,
      (__attribute__((address_space(3))) void*)l, 16, 0, 0);
}

// ---- fused weight transpose + bf16 hi/lo split for all 6 weights ----
struct TrArgs {
  const float* W[6];
  unsigned short* Wh[6];
  unsigned short* Wl[6];
  int K[6];
};

__global__ __launch_bounds__(256) void tr_all_k(TrArgs a) {
  const int z = blockIdx.z;
  const int K = a.K[z];
  if (blockIdx.x * 64 >= K) return;
  const float* W = a.W[z];
  unsigned short* Wt_hi = a.Wh[z];
  unsigned short* Wt_lo = a.Wl[z];
  __shared__ float t[64][65];
  const int k0 = blockIdx.x * 64, n0 = blockIdx.y * 64;
  const int tid = threadIdx.x;
  const int rr = tid >> 4, c4 = (tid & 15) * 4;
#pragma unroll
  for (int q = 0; q < 4; ++q) {
    int row = q * 16 + rr;
    const float4 v = *reinterpret_cast<const float4*>(W + (size_t)(k0 + row) * 256 + n0 + c4);
    t[row][c4 + 0] = v.x; t[row][c4 + 1] = v.y; t[row][c4 + 2] = v.z; t[row][c4 + 3] = v.w;
  }
  __syncthreads();
#pragma unroll
  for (int q = 0; q < 4; ++q) {
    int n = q * 16 + rr;
    ushort4 oh, ol;
    float w0 = t[c4 + 0][n], w1 = t[c4 + 1][n], w2 = t[c4 + 2][n], w3 = t[c4 + 3][n];
    oh.x = f2bf(w0); ol.x = f2bf(w0 - bf2f(oh.x));
    oh.y = f2bf(w1); ol.y = f2bf(w1 - bf2f(oh.y));
    oh.z = f2bf(w2); ol.z = f2bf(w2 - bf2f(oh.z));
    oh.w = f2bf(w3); ol.w = f2bf(w3 - bf2f(oh.w));
    *reinterpret_cast<ushort4*>(Wt_hi + (size_t)(n0 + n) * K + k0 + c4) = oh;
    *reinterpret_cast<ushort4*>(Wt_lo + (size_t)(n0 + n) * K + k0 + c4) = ol;
  }
}

// =============== CSR build via 2-level bucket sort ===============
// Level 1: histogram + partition edges into NB3 buckets (1024 rows each),
// LDS-grouped so global writes are bucket-sorted runs (coalesced).
// Level 2: one block per bucket builds row_ptr and the final row-sorted cv
// inside an L2-resident window.

__global__ __launch_bounds__(256) void bcount_k(
    const int* __restrict__ r0, const int* __restrict__ r1, const int* __restrict__ r2,
    int* __restrict__ bcnt)
{
  __shared__ int h[NB3];
  const int t = threadIdx.x;
  for (int i = t; i < NB3; i += 256) h[i] = 0;
  __syncthreads();
  const long long cbase = (long long)blockIdx.x * CHUNK;
  const long long tot = 3LL * N_EDGES;
#pragma unroll
  for (int j = 0; j < 16; ++j) {
    long long idx = cbase + j * 256 + t;
    if (idx < tot) {
      int g = (int)(idx / N_EDGES);
      int e = (int)(idx - (long long)g * N_EDGES);
      int row = (g == 0 ? r0 : g == 1 ? r1 : r2)[e];
      atomicAdd(&h[g * BKT + (row >> 10)], 1);
    }
  }
  __syncthreads();
  for (int i = t; i < NB3; i += 256)
    if (h[i]) atomicAdd(&bcnt[i], h[i]);
}

__global__ void bscan_k(const int* __restrict__ bcnt, int* __restrict__ flatBase,
                        int* __restrict__ cursor) {
  __shared__ int c[NB3];
  const int t = threadIdx.x;
  if (t < NB3) c[t] = bcnt[t];
  __syncthreads();
  if (t < 3) {
    int acc = t * N_EDGES;
    for (int b = 0; b < BKT; ++b) {
      int i = t * BKT + b;
      int v = c[i];
      flatBase[i] = acc;
      cursor[i] = acc;
      acc += v;
    }
  }
  if (t == 0) flatBase[NB3] = 3 * N_EDGES;
}

__global__ __launch_bounds__(256) void bpart_k(
    const int* __restrict__ r0, const int* __restrict__ c0, const float* __restrict__ v0,
    const int* __restrict__ r1, const int* __restrict__ c1, const float* __restrict__ v1,
    const int* __restrict__ r2, const int* __restrict__ c2, const float* __restrict__ v2,
    int* __restrict__ cursor, int2* __restrict__ packed)
{
  __shared__ int hs[256];       // hist (first NB3) then inclusive scan
  __shared__ int ls[NB3];       // frozen local exclusive starts
  __shared__ int cur[NB3];      // running local cursor
  __shared__ int clm[NB3];      // claimed global base per bucket
  __shared__ int2 stg[CHUNK];
  __shared__ int tgt[CHUNK];
  const int t = threadIdx.x;
  const long long cbase = (long long)blockIdx.x * CHUNK;
  const long long tot = 3LL * N_EDGES;
  hs[t] = 0;
  __syncthreads();
  int rows_[16], gbs_[16];
#pragma unroll
  for (int j = 0; j < 16; ++j) {
    long long idx = cbase + j * 256 + t;
    int gb = -1, row = 0;
    if (idx < tot) {
      int g = (int)(idx / N_EDGES);
      int e = (int)(idx - (long long)g * N_EDGES);
      row = (g == 0 ? r0 : g == 1 ? r1 : r2)[e];
      gb = g * BKT + (row >> 10);
      atomicAdd(&hs[gb], 1);
    }
    gbs_[j] = gb; rows_[j] = row;
  }
  __syncthreads();
  const int myh = hs[t];
  if (t < NB3) clm[t] = atomicAdd(&cursor[t], myh);
  // inclusive scan of hs[0..255]
  for (int off = 1; off < 256; off <<= 1) {
    int v = (t >= off) ? hs[t - off] : 0;
    __syncthreads();
    hs[t] += v;
    __syncthreads();
  }
  const int excl = hs[t] - myh;
  if (t < NB3) { ls[t] = excl; cur[t] = excl; }
  __syncthreads();
#pragma unroll
  for (int j = 0; j < 16; ++j) {
    const int gb = gbs_[j];
    if (gb >= 0) {
      long long idx = cbase + j * 256 + t;
      int g = (int)(idx / N_EDGES);
      int e = (int)(idx - (long long)g * N_EDGES);
      int col = (g == 0 ? c0 : g == 1 ? c1 : c2)[e];
      float vv = (g == 0 ? v0 : g == 1 ? v1 : v2)[e];
      int slot = atomicAdd(&cur[gb], 1);
      stg[slot] = make_int2(rows_[j] | (col << 16), __float_as_int(vv));
      tgt[slot] = clm[gb] + (slot - ls[gb]);
    }
  }
  __syncthreads();
  const int cnt = (int)min((long long)CHUNK, tot - cbase);
  for (int i = t; i < cnt; i += 256) packed[tgt[i]] = stg[i];
}

__global__ __launch_bounds__(256) void bfinal_k(
    const int2* __restrict__ packed, const int* __restrict__ flatBase,
    int* __restrict__ row_ptr3, int2* __restrict__ cv3)
{
  __shared__ int hist[BROWS];
  __shared__ int part[256];
  const int gb = blockIdx.x;
  const int g = gb / BKT, b = gb % BKT;
  const int rb = b * BROWS;
  const int nrows = min(BROWS, N_NODES - rb);
  const int base = flatBase[gb];
  const int cnt = flatBase[gb + 1] - base;
  const int cvb = base - g * N_EDGES;
  const int t = threadIdx.x;
  for (int i = t; i < BROWS; i += 256) hist[i] = 0;
  __syncthreads();
  for (int i = t; i < cnt; i += 256) {
    int rc = packed[base + i].x;
    atomicAdd(&hist[(rc & 0xffff) - rb], 1);
  }
  __syncthreads();
  const int l0 = hist[4 * t], l1 = hist[4 * t + 1], l2 = hist[4 * t + 2], l3 = hist[4 * t + 3];
  const int s = l0 + l1 + l2 + l3;
  part[t] = s;
  __syncthreads();
  for (int off = 1; off < 256; off <<= 1) {
    int v = (t >= off) ? part[t - off] : 0;
    __syncthreads();
    part[t] += v;
    __syncthreads();
  }
  const int pexcl = part[t] - s;
  const int e0 = pexcl, e1 = e0 + l0, e2 = e1 + l1, e3 = e2 + l2;
  hist[4 * t] = e0; hist[4 * t + 1] = e1; hist[4 * t + 2] = e2; hist[4 * t + 3] = e3;
  int* rp = row_ptr3 + (size_t)g * (N_NODES + 1);
  if (4 * t + 0 < nrows) rp[rb + 4 * t + 0] = cvb + e0;
  if (4 * t + 1 < nrows) rp[rb + 4 * t + 1] = cvb + e1;
  if (4 * t + 2 < nrows) rp[rb + 4 * t + 2] = cvb + e2;
  if (4 * t + 3 < nrows) rp[rb + 4 * t + 3] = cvb + e3;
  if (rb + BROWS >= N_NODES && t == 0) rp[N_NODES] = N_EDGES;
  __syncthreads();
  for (int i = t; i < cnt; i += 256) {
    int2 p = packed[base + i];
    int row = p.x & 0xffff;
    int col = ((unsigned)p.x) >> 16;
    int pos = atomicAdd(&hist[row - rb], 1);
    cv3[base + pos] = make_int2(col, p.y);
  }
}

__global__ void flag_k(const int* __restrict__ ids, unsigned char* __restrict__ flag, int B) {
  int i = blockIdx.x * blockDim.x + threadIdx.x;
  if (i < B) flag[ids[i]] = 1;
}

// ---------------- SpMM: f32 src/dst, CSR, one wave per row ----------------
__global__ __launch_bounds__(256) void spmm_k(
    const int* __restrict__ row_ptr, const int2* __restrict__ cv,
    const float* __restrict__ src, float* __restrict__ dst,
    const float* __restrict__ bias, int do_leaky,
    const unsigned char* __restrict__ flag, int n)
{
  int r = (blockIdx.x << 2) + (threadIdx.x >> 6);
  if (r >= n) return;
  if (flag && !flag[r]) return;
  const int lane = threadIdx.x & 63;
  const int c0 = lane << 2;
  int e0 = row_ptr[r], e1 = row_ptr[r + 1];
  float a0 = 0.f, a1 = 0.f, a2 = 0.f, a3 = 0.f;
  int e = e0;
  for (; e + 1 < e1; e += 2) {
    int2 p = cv[e];
    int2 q = cv[e + 1];
    float v = __int_as_float(p.y);
    float w = __int_as_float(q.y);
    const float4 x = *reinterpret_cast<const float4*>(src + (size_t)p.x * D_DIM + c0);
    const float4 y = *reinterpret_cast<const float4*>(src + (size_t)q.x * D_DIM + c0);
    a0 = fmaf(v, x.x, a0); a1 = fmaf(v, x.y, a1);
    a2 = fmaf(v, x.z, a2); a3 = fmaf(v, x.w, a3);
    a0 = fmaf(w, y.x, a0); a1 = fmaf(w, y.y, a1);
    a2 = fmaf(w, y.z, a2); a3 = fmaf(w, y.w, a3);
  }
  for (; e < e1; ++e) {
    int2 p = cv[e];
    float v = __int_as_float(p.y);
    const float4 x = *reinterpret_cast<const float4*>(src + (size_t)p.x * D_DIM + c0);
    a0 = fmaf(v, x.x, a0); a1 = fmaf(v, x.y, a1);
    a2 = fmaf(v, x.z, a2); a3 = fmaf(v, x.w, a3);
  }
  if (bias) {
    const float4 b = *reinterpret_cast<const float4*>(bias + c0);
    a0 += b.x; a1 += b.y; a2 += b.z; a3 += b.w;
  }
  if (do_leaky) {
    a0 = a0 > 0.f ? a0 : 0.01f * a0;
    a1 = a1 > 0.f ? a1 : 0.01f * a1;
    a2 = a2 > 0.f ? a2 : 0.01f * a2;
    a3 = a3 > 0.f ? a3 : 0.01f * a3;
  }
  *reinterpret_cast<float4*>(dst + (size_t)r * D_DIM + c0) =
      make_float4(a0, a1, a2, a3);
}

// ---------------- MFMA GEMM, split-precision bf16 (3-term), LDS B-staging ----
// 128-row tile, 512 threads (8 waves = 4M x 2N). Per 32-K chunk the block
// stages the 256x32 hi+lo B-tiles (32 KB) via global_load_lds width-16;
// linear LDS dest, k-segment permutation applied on the global source and on
// the ds_read slot (both-sides), 2-way (free) bank pattern.
// MODE 0: C = A@W (+bias)      MODE 1: C = leaky(A@W + bias)
// MODE 2: g = sigmoid(A@W+bias); C = g*nxt[row] + (1-g)*hin[rowidx?rowidx[row]:row]
template<int KT, int MODE>
__global__ __launch_bounds__(512, 4) void mm_k(
    const float* __restrict__ Aptr,
    const unsigned short* __restrict__ Wt_hi,
    const unsigned short* __restrict__ Wt_lo,
    const float* __restrict__ bias,
    float* __restrict__ C, int ldc, int ccol0, int M,
    const int* __restrict__ rowidx,
    const float* __restrict__ nxt, const float* __restrict__ hin)
{
  __shared__ __align__(16) unsigned char smem[32768];  // hi: [0,16K), lo: [16K,32K)
  const int tid = threadIdx.x;
  const int wid = tid >> 6, lane = tid & 63;
  const int wm = wid & 3, wn = wid >> 2;       // 4 (M) x 2 (N) waves
  const int bm = blockIdx.x * 128;
  const int l15 = lane & 15, lk = lane >> 4;   // k-group 0..3

  int mrow[2];
  const float* arow[2];
#pragma unroll
  for (int mi = 0; mi < 2; ++mi) {
    int m = bm + wm * 32 + mi * 16 + l15;
    mrow[mi] = m;
    int sr = (m < M) ? (rowidx ? rowidx[m] : m) : 0;
    arow[mi] = Aptr + (size_t)sr * KT;
  }

  // staging: segment s in [0,1024): n=s>>2, k-seg=((s&3)-((s>>3)&3))&3
  const int s1 = tid, s2 = tid + 512;
  const size_t go1 = (size_t)(s1 >> 2) * KT + ((((s1 & 3) - ((s1 >> 3) & 3)) & 3) << 3);
  const size_t go2 = (size_t)(s2 >> 2) * KT + ((((s2 & 3) - ((s2 >> 3) & 3)) & 3) << 3);

  f32x4 acc[2][8] = {};
  for (int kc = 0; kc < KT / 32; ++kc) {
    const int kk = kc * 32;
    __syncthreads();   // previous chunk's reads complete before overwrite
    glds16(Wt_hi + go1 + kk, smem + s1 * 16);
    glds16(Wt_hi + go2 + kk, smem + s2 * 16);
    glds16(Wt_lo + go1 + kk, smem + 16384 + s1 * 16);
    glds16(Wt_lo + go2 + kk, smem + 16384 + s2 * 16);
    // A fragments (overlap with staging latency)
    const int ka = kk + lk * 8;
    bf16x8 ah[2], al[2];
#pragma unroll
    for (int mi = 0; mi < 2; ++mi) {
      bf16x8 th = {0, 0, 0, 0, 0, 0, 0, 0};
      bf16x8 tl = {0, 0, 0, 0, 0, 0, 0, 0};
      if (mrow[mi] < M) {
        const float* p = arow[mi] + ka;
        const float4 x = *reinterpret_cast<const float4*>(p);
        const float4 y = *reinterpret_cast<const float4*>(p + 4);
#define SPLIT_A(i, val) { unsigned short h_ = f2bf(val); th[i] = (short)h_; \
                          tl[i] = (short)f2bf((val) - bf2f(h_)); }
        SPLIT_A(0, x.x) SPLIT_A(1, x.y) SPLIT_A(2, x.z) SPLIT_A(3, x.w)
        SPLIT_A(4, y.x) SPLIT_A(5, y.y) SPLIT_A(6, y.z) SPLIT_A(7, y.w)
#undef SPLIT_A
      }
      ah[mi] = th; al[mi] = tl;
    }
    __syncthreads();   // staging drained (vmcnt(0)+barrier)
#pragma unroll
    for (int f = 0; f < 8; ++f) {
      const int n = wn * 128 + f * 16 + l15;
      const int boff = n * 64 + (((lk + (l15 >> 1)) & 3) << 4);
      const bf16x8 bh = *reinterpret_cast<const bf16x8*>(smem + boff);
      const bf16x8 bl = *reinterpret_cast<const bf16x8*>(smem + 16384 + boff);
#pragma unroll
      for (int mi = 0; mi < 2; ++mi) {
        acc[mi][f] = __builtin_amdgcn_mfma_f32_16x16x32_bf16(ah[mi], bh, acc[mi][f], 0, 0, 0);
        acc[mi][f] = __builtin_amdgcn_mfma_f32_16x16x32_bf16(al[mi], bh, acc[mi][f], 0, 0, 0);
        acc[mi][f] = __builtin_amdgcn_mfma_f32_16x16x32_bf16(ah[mi], bl, acc[mi][f], 0, 0, 0);
      }
    }
  }

  __syncthreads();   // in-place safety: all A reads in block done before writes

#pragma unroll
  for (int mi = 0; mi < 2; ++mi) {
    const int rbase = bm + wm * 32 + mi * 16 + lk * 4;
    int hsrc[4];
    if (MODE == 2) {
#pragma unroll
      for (int r = 0; r < 4; ++r) {
        const int row = rbase + r;
        hsrc[r] = (rowidx && row < M) ? rowidx[row] : row;
      }
    }
#pragma unroll
    for (int f = 0; f < 8; ++f) {
      const int col = wn * 128 + f * 16 + l15;
      const float bc = bias ? bias[col] : 0.f;
#pragma unroll
      for (int r = 0; r < 4; ++r) {
        const int row = rbase + r;
        if (row >= M) continue;
        float v = acc[mi][f][r] + bc;
        if (MODE == 1) v = v > 0.f ? v : 0.01f * v;
        if (MODE == 2) {
          const float g = 1.f / (1.f + __expf(-v));
          const float nv = nxt[(size_t)row * D_DIM + col];
          const float hv = hin[(size_t)hsrc[r] * D_DIM + col];
          v = g * nv + (1.f - g) * hv;
        }
        C[(size_t)row * ldc + ccol0 + col] = v;
      }
    }
  }
}

// ---------------- row gather (f32 src -> f32 out columns) ----------------
__global__ __launch_bounds__(256) void gather_k(const float* __restrict__ src,
                                                const int* __restrict__ ids,
                                                float* __restrict__ dst, int ccol0, int B)
{
  int i = (blockIdx.x << 2) + (threadIdx.x >> 6);
  if (i >= B) return;
  const int lane = threadIdx.x & 63;
  const int c0 = lane << 2;
  const float4 v = *reinterpret_cast<const float4*>(src + (size_t)ids[i] * D_DIM + c0);
  *reinterpret_cast<float4*>(dst + (size_t)i * 1024 + ccol0 + c0) = v;
}

// ---------------- launch ----------------
extern "C" void kernel_launch(void* const* d_in, const int* in_sizes, int n_in,
                              void* d_out, int out_size, void* d_ws, size_t ws_size,
                              hipStream_t stream)
{
  const float* ent_lit = (const float*)d_in[0];
  const float* rel_lit = (const float*)d_in[1];
  const float* attr_lit = (const float*)d_in[2];
  const float* ent_val = (const float*)d_in[3];
  const float* rel_val = (const float*)d_in[4];
  const float* attr_val = (const float*)d_in[5];
  const float* W_ent = (const float*)d_in[6];
  const float* b_ent = (const float*)d_in[7];
  const float* W_rel = (const float*)d_in[8];
  const float* b_rel = (const float*)d_in[9];
  const float* W_attr = (const float*)d_in[10];
  const float* b_attr = (const float*)d_in[11];
  const float* W_x = (const float*)d_in[12];
  const float* b_x = (const float*)d_in[13];
  const float* W_lit = (const float*)d_in[14];
  const float* b_lit = (const float*)d_in[15];
  const float* W_gate = (const float*)d_in[16];
  const float* b_gate = (const float*)d_in[17];
  const int* ent_row = (const int*)d_in[18];
  const int* ent_col = (const int*)d_in[19];
  const int* rel_row = (const int*)d_in[20];
  const int* rel_col = (const int*)d_in[21];
  const int* attr_row = (const int*)d_in[22];
  const int* attr_col = (const int*)d_in[23];
  const int* ent_ids = (const int*)d_in[24];
  float* out = (float*)d_out;

  char* p = (char*)d_ws;
  const size_t bufsz = alignup((size_t)N_NODES * D_DIM * 4);
  const size_t wsz_f = alignup((size_t)F_DIM * D_DIM * 2);
  const size_t wsz_d = alignup((size_t)D_DIM * D_DIM * 2);
  float* B0 = (float*)p; p += bufsz;
  float* B1 = (float*)p; p += bufsz;
  float* P  = (float*)p; p += alignup((size_t)B_IDS * D_DIM * 4);
  unsigned short* Wh_ent = (unsigned short*)p; p += wsz_f;
  unsigned short* Wl_ent = (unsigned short*)p; p += wsz_f;
  unsigned short* Wh_rel = (unsigned short*)p; p += wsz_f;
  unsigned short* Wl_rel = (unsigned short*)p; p += wsz_f;
  unsigned short* Wh_attr = (unsigned short*)p; p += wsz_f;
  unsigned short* Wl_attr = (unsigned short*)p; p += wsz_f;
  unsigned short* Wh_lit = (unsigned short*)p; p += wsz_f;
  unsigned short* Wl_lit = (unsigned short*)p; p += wsz_f;
  unsigned short* Wh_x = (unsigned short*)p; p += wsz_d;
  unsigned short* Wl_x = (unsigned short*)p; p += wsz_d;
  unsigned short* Wh_gate = (unsigned short*)p; p += wsz_d;
  unsigned short* Wl_gate = (unsigned short*)p; p += wsz_d;
  int* row_ptr3 = (int*)p; p += alignup((size_t)3 * (N_NODES + 1) * 4);
  int* bcnt = (int*)p; p += alignup((size_t)NB3 * 4);
  int* flatBase = (int*)p; p += alignup((size_t)(NB3 + 1) * 4);
  int* cursor = (int*)p; p += alignup((size_t)NB3 * 4);
  unsigned char* flags = (unsigned char*)p; p += alignup((size_t)N_NODES);
  int2* cv3 = (int2*)p; p += alignup((size_t)3 * N_EDGES * 8);
  if ((size_t)(p - (char*)d_ws) > ws_size) return;

  // packed edge buffer aliases B0 (dead until first mm_k, which runs after bfinal)
  int2* packed = (int2*)B0;

  const int* rp_ent = row_ptr3;
  const int* rp_rel = row_ptr3 + (N_NODES + 1);
  const int* rp_attr = row_ptr3 + 2 * (N_NODES + 1);
  const int2* cv_ent = cv3;
  const int2* cv_rel = cv3 + (size_t)N_EDGES;
  const int2* cv_attr = cv3 + (size_t)2 * N_EDGES;

  dim3 blk(256), blk512(512);
  const int nchunks = (int)((3LL * N_EDGES + CHUNK - 1) / CHUNK);
  dim3 g_spmm((N_NODES + 3) / 4);
  dim3 g_gather((B_IDS + 3) / 4);
  dim3 g_mm_big((N_NODES + 127) / 128);
  dim3 g_mm_ids(B_IDS / 128);

  // weights -> bf16 hi/lo transposed (one fused launch)
  TrArgs ta;
  ta.W[0] = W_ent;  ta.Wh[0] = Wh_ent;  ta.Wl[0] = Wl_ent;  ta.K[0] = F_DIM;
  ta.W[1] = W_rel;  ta.Wh[1] = Wh_rel;  ta.Wl[1] = Wl_rel;  ta.K[1] = F_DIM;
  ta.W[2] = W_attr; ta.Wh[2] = Wh_attr; ta.Wl[2] = Wl_attr; ta.K[2] = F_DIM;
  ta.W[3] = W_lit;  ta.Wh[3] = Wh_lit;  ta.Wl[3] = Wl_lit;  ta.K[3] = F_DIM;
  ta.W[4] = W_x;    ta.Wh[4] = Wh_x;    ta.Wl[4] = Wl_x;    ta.K[4] = D_DIM;
  ta.W[5] = W_gate; ta.Wh[5] = Wh_gate; ta.Wl[5] = Wl_gate; ta.K[5] = D_DIM;
  tr_all_k<<<dim3(F_DIM / 64, 4, 6), blk, 0, stream>>>(ta);

  // CSR build (bucket sort)
  hipMemsetAsync(bcnt, 0, NB3 * sizeof(int), stream);
  bcount_k<<<dim3(nchunks), blk, 0, stream>>>(ent_row, rel_row, attr_row, bcnt);
  bscan_k<<<dim3(1), blk, 0, stream>>>(bcnt, flatBase, cursor);
  bpart_k<<<dim3(nchunks), blk, 0, stream>>>(ent_row, ent_col, ent_val,
                                             rel_row, rel_col, rel_val,
                                             attr_row, attr_col, attr_val,
                                             cursor, packed);
  bfinal_k<<<dim3(NB3), blk, 0, stream>>>(packed, flatBase, row_ptr3, cv3);

  // flags for row restriction (rows observed via ent_ids)
  hipMemsetAsync(flags, 0, N_NODES, stream);
  flag_k<<<dim3(B_IDS / 256), blk, 0, stream>>>(ent_ids, flags, B_IDS);

  // ----- rel branch -> out[:,512:768]
  mm_k<F_DIM, 0><<<g_mm_big, blk512, 0, stream>>>(rel_lit, Wh_rel, Wl_rel, nullptr, B0, D_DIM, 0,
                                                  N_NODES, nullptr, nullptr, nullptr);
  spmm_k<<<g_spmm, blk, 0, stream>>>(rp_rel, cv_rel, B0, B1, b_rel, 1, flags, N_NODES);
  gather_k<<<g_gather, blk, 0, stream>>>(B1, ent_ids, out, 512, B_IDS);

  // ----- attr branch -> out[:,768:1024]
  mm_k<F_DIM, 0><<<g_mm_big, blk512, 0, stream>>>(attr_lit, Wh_attr, Wl_attr, nullptr, B0, D_DIM, 0,
                                                  N_NODES, nullptr, nullptr, nullptr);
  spmm_k<<<g_spmm, blk, 0, stream>>>(rp_attr, cv_attr, B0, B1, b_attr, 1, flags, N_NODES);
  gather_k<<<g_gather, blk, 0, stream>>>(B1, ent_ids, out, 768, B_IDS);

  // ----- ent literals -> out[:,0:256]
  mm_k<F_DIM, 0><<<g_mm_ids, blk512, 0, stream>>>(ent_lit, Wh_lit, Wl_lit, b_lit, out, 1024, 0,
                                                  B_IDS, ent_ids, nullptr, nullptr);

  // ----- ent n-hop -----
  mm_k<F_DIM, 0><<<g_mm_big, blk512, 0, stream>>>(ent_lit, Wh_ent, Wl_ent, nullptr, B0, D_DIM, 0,
                                                  N_NODES, nullptr, nullptr, nullptr);
  spmm_k<<<g_spmm, blk, 0, stream>>>(rp_ent, cv_ent, B0, B1, b_ent, 1, nullptr, N_NODES); // h1=B1
  // hop 2 (all rows; nxt and h2 computed in place)
  spmm_k<<<g_spmm, blk, 0, stream>>>(rp_ent, cv_ent, B1, B0, nullptr, 0, nullptr, N_NODES); // s2=B0
  mm_k<D_DIM, 1><<<g_mm_big, blk512, 0, stream>>>(B0, Wh_x, Wl_x, b_x, B0, D_DIM, 0,
                                                  N_NODES, nullptr, nullptr, nullptr);  // nxt2=B0
  mm_k<D_DIM, 2><<<g_mm_big, blk512, 0, stream>>>(B1, Wh_gate, Wl_gate, b_gate, B1, D_DIM, 0,
                                                  N_NODES, nullptr, B0, B1);            // h2=B1
  // hop 3 (only rows observed via ent_ids)
  spmm_k<<<g_spmm, blk, 0, stream>>>(rp_ent, cv_ent, B1, B0, nullptr, 0, flags, N_NODES); // s3=B0
  mm_k<D_DIM, 1><<<g_mm_ids, blk512, 0, stream>>>(B0, Wh_x, Wl_x, b_x, P, D_DIM, 0,
                                                  B_IDS, ent_ids, nullptr, nullptr);    // nxt3
  mm_k<D_DIM, 2><<<g_mm_ids, blk512, 0, stream>>>(B1, Wh_gate, Wl_gate, b_gate, out, 1024, 256,
                                                  B_IDS, ent_ids, P, B1);               // -> out[:,256:512]
}

// Round 8
// 1302.235 us; speedup vs baseline: 2.6766x; 1.2008x over previous
//
#include <hip/hip_runtime.h>
#include <math.h>

#define N_NODES 50000
#define N_EDGES 1600000
#define F_DIM 1024
#define D_DIM 256
#define B_IDS 16384

#define BROWS 1024            // rows per bucket
#define BKT 49                // buckets per graph (ceil(50000/1024))
#define NB3 (3 * BKT)         // 147
#define CHUNK 4096            // edges per partition block

typedef __attribute__((ext_vector_type(8))) short bf16x8;
typedef __attribute__((ext_vector_type(4))) float f32x4;

static inline size_t alignup(size_t x) { return (x + 255) & ~(size_t)255; }

__device__ inline unsigned short f2bf(float f) {
  unsigned u = __float_as_uint(f);
  u += 0x7fffu + ((u >> 16) & 1u);   // RNE (inputs are finite)
  return (unsigned short)(u >> 16);
}
__device__ inline float bf2f(unsigned short u) {
  return __uint_as_float(((unsigned)u) << 16);
}

__device__ inline void glds16(const void* g, void* l) {
  __builtin_amdgcn_global_load_lds(
      (const __attribute__((address_space(1))) void*)g,
      (__attribute__((address_space(3))) void*)l, 16, 0, 0);
}

// ---- fused weight transpose + bf16 hi/lo split for all 6 weights ----
struct TrArgs {
  const float* W[6];
  unsigned short* Wh[6];
  unsigned short* Wl[6];
  int K[6];
};

__global__ __launch_bounds__(256) void tr_all_k(TrArgs a) {
  const int z = blockIdx.z;
  const int K = a.K[z];
  if (blockIdx.x * 64 >= K) return;
  const float* W = a.W[z];
  unsigned short* Wt_hi = a.Wh[z];
  unsigned short* Wt_lo = a.Wl[z];
  __shared__ float t[64][65];
  const int k0 = blockIdx.x * 64, n0 = blockIdx.y * 64;
  const int tid = threadIdx.x;
  const int rr = tid >> 4, c4 = (tid & 15) * 4;
#pragma unroll
  for (int q = 0; q < 4; ++q) {
    int row = q * 16 + rr;
    const float4 v = *reinterpret_cast<const float4*>(W + (size_t)(k0 + row) * 256 + n0 + c4);
    t[row][c4 + 0] = v.x; t[row][c4 + 1] = v.y; t[row][c4 + 2] = v.z; t[row][c4 + 3] = v.w;
  }
  __syncthreads();
#pragma unroll
  for (int q = 0; q < 4; ++q) {
    int n = q * 16 + rr;
    ushort4 oh, ol;
    float w0 = t[c4 + 0][n], w1 = t[c4 + 1][n], w2 = t[c4 + 2][n], w3 = t[c4 + 3][n];
    oh.x = f2bf(w0); ol.x = f2bf(w0 - bf2f(oh.x));
    oh.y = f2bf(w1); ol.y = f2bf(w1 - bf2f(oh.y));
    oh.z = f2bf(w2); ol.z = f2bf(w2 - bf2f(oh.z));
    oh.w = f2bf(w3); ol.w = f2bf(w3 - bf2f(oh.w));
    *reinterpret_cast<ushort4*>(Wt_hi + (size_t)(n0 + n) * K + k0 + c4) = oh;
    *reinterpret_cast<ushort4*>(Wt_lo + (size_t)(n0 + n) * K + k0 + c4) = ol;
  }
}

// =============== CSR build via 2-level bucket sort ===============

__global__ __launch_bounds__(256) void bcount_k(
    const int* __restrict__ r0, const int* __restrict__ r1, const int* __restrict__ r2,
    int* __restrict__ bcnt)
{
  __shared__ int h[NB3];
  const int t = threadIdx.x;
  for (int i = t; i < NB3; i += 256) h[i] = 0;
  __syncthreads();
  const long long cbase = (long long)blockIdx.x * CHUNK;
  const long long tot = 3LL * N_EDGES;
#pragma unroll
  for (int j = 0; j < 16; ++j) {
    long long idx = cbase + j * 256 + t;
    if (idx < tot) {
      int g = (int)(idx / N_EDGES);
      int e = (int)(idx - (long long)g * N_EDGES);
      int row = (g == 0 ? r0 : g == 1 ? r1 : r2)[e];
      atomicAdd(&h[g * BKT + (row >> 10)], 1);
    }
  }
  __syncthreads();
  for (int i = t; i < NB3; i += 256)
    if (h[i]) atomicAdd(&bcnt[i], h[i]);
}

__global__ void bscan_k(const int* __restrict__ bcnt, int* __restrict__ flatBase,
                        int* __restrict__ cursor) {
  __shared__ int c[NB3];
  const int t = threadIdx.x;
  if (t < NB3) c[t] = bcnt[t];
  __syncthreads();
  if (t < 3) {
    int acc = t * N_EDGES;
    for (int b = 0; b < BKT; ++b) {
      int i = t * BKT + b;
      int v = c[i];
      flatBase[i] = acc;
      cursor[i] = acc;
      acc += v;
    }
  }
  if (t == 0) flatBase[NB3] = 3 * N_EDGES;
}

__global__ __launch_bounds__(256) void bpart_k(
    const int* __restrict__ r0, const int* __restrict__ c0, const float* __restrict__ v0,
    const int* __restrict__ r1, const int* __restrict__ c1, const float* __restrict__ v1,
    const int* __restrict__ r2, const int* __restrict__ c2, const float* __restrict__ v2,
    int* __restrict__ cursor, int2* __restrict__ packed)
{
  __shared__ int hs[256];
  __shared__ int ls[NB3];
  __shared__ int cur[NB3];
  __shared__ int clm[NB3];
  __shared__ int2 stg[CHUNK];
  __shared__ int tgt[CHUNK];
  const int t = threadIdx.x;
  const long long cbase = (long long)blockIdx.x * CHUNK;
  const long long tot = 3LL * N_EDGES;
  hs[t] = 0;
  __syncthreads();
  int rows_[16], gbs_[16];
#pragma unroll
  for (int j = 0; j < 16; ++j) {
    long long idx = cbase + j * 256 + t;
    int gb = -1, row = 0;
    if (idx < tot) {
      int g = (int)(idx / N_EDGES);
      int e = (int)(idx - (long long)g * N_EDGES);
      row = (g == 0 ? r0 : g == 1 ? r1 : r2)[e];
      gb = g * BKT + (row >> 10);
      atomicAdd(&hs[gb], 1);
    }
    gbs_[j] = gb; rows_[j] = row;
  }
  __syncthreads();
  const int myh = hs[t];
  if (t < NB3) clm[t] = atomicAdd(&cursor[t], myh);
  for (int off = 1; off < 256; off <<= 1) {
    int v = (t >= off) ? hs[t - off] : 0;
    __syncthreads();
    hs[t] += v;
    __syncthreads();
  }
  const int excl = hs[t] - myh;
  if (t < NB3) { ls[t] = excl; cur[t] = excl; }
  __syncthreads();
#pragma unroll
  for (int j = 0; j < 16; ++j) {
    const int gb = gbs_[j];
    if (gb >= 0) {
      long long idx = cbase + j * 256 + t;
      int g = (int)(idx / N_EDGES);
      int e = (int)(idx - (long long)g * N_EDGES);
      int col = (g == 0 ? c0 : g == 1 ? c1 : c2)[e];
      float vv = (g == 0 ? v0 : g == 1 ? v1 : v2)[e];
      int slot = atomicAdd(&cur[gb], 1);
      stg[slot] = make_int2(rows_[j] | (col << 16), __float_as_int(vv));
      tgt[slot] = clm[gb] + (slot - ls[gb]);
    }
  }
  __syncthreads();
  const int cnt = (int)min((long long)CHUNK, tot - cbase);
  for (int i = t; i < cnt; i += 256) packed[tgt[i]] = stg[i];
}

__global__ __launch_bounds__(256) void bfinal_k(
    const int2* __restrict__ packed, const int* __restrict__ flatBase,
    int* __restrict__ row_ptr3, int2* __restrict__ cv3)
{
  __shared__ int hist[BROWS];
  __shared__ int part[256];
  const int gb = blockIdx.x;
  const int g = gb / BKT, b = gb % BKT;
  const int rb = b * BROWS;
  const int nrows = min(BROWS, N_NODES - rb);
  const int base = flatBase[gb];
  const int cnt = flatBase[gb + 1] - base;
  const int cvb = base - g * N_EDGES;
  const int t = threadIdx.x;
  for (int i = t; i < BROWS; i += 256) hist[i] = 0;
  __syncthreads();
  for (int i = t; i < cnt; i += 256) {
    int rc = packed[base + i].x;
    atomicAdd(&hist[(rc & 0xffff) - rb], 1);
  }
  __syncthreads();
  const int l0 = hist[4 * t], l1 = hist[4 * t + 1], l2 = hist[4 * t + 2], l3 = hist[4 * t + 3];
  const int s = l0 + l1 + l2 + l3;
  part[t] = s;
  __syncthreads();
  for (int off = 1; off < 256; off <<= 1) {
    int v = (t >= off) ? part[t - off] : 0;
    __syncthreads();
    part[t] += v;
    __syncthreads();
  }
  const int pexcl = part[t] - s;
  const int e0 = pexcl, e1 = e0 + l0, e2 = e1 + l1, e3 = e2 + l2;
  hist[4 * t] = e0; hist[4 * t + 1] = e1; hist[4 * t + 2] = e2; hist[4 * t + 3] = e3;
  int* rp = row_ptr3 + (size_t)g * (N_NODES + 1);
  if (4 * t + 0 < nrows) rp[rb + 4 * t + 0] = cvb + e0;
  if (4 * t + 1 < nrows) rp[rb + 4 * t + 1] = cvb + e1;
  if (4 * t + 2 < nrows) rp[rb + 4 * t + 2] = cvb + e2;
  if (4 * t + 3 < nrows) rp[rb + 4 * t + 3] = cvb + e3;
  if (rb + BROWS >= N_NODES && t == 0) rp[N_NODES] = N_EDGES;
  __syncthreads();
  for (int i = t; i < cnt; i += 256) {
    int2 p = packed[base + i];
    int row = p.x & 0xffff;
    int col = ((unsigned)p.x) >> 16;
    int pos = atomicAdd(&hist[row - rb], 1);
    cv3[base + pos] = make_int2(col, p.y);
  }
}

__global__ void flag_k(const int* __restrict__ ids, unsigned char* __restrict__ flag, int B) {
  int i = blockIdx.x * blockDim.x + threadIdx.x;
  if (i < B) flag[ids[i]] = 1;
}

// ---------------- SpMM: bf16 gather, f32 accumulate/out (+opt bf16 shadow) ----
// Halves gather bytes vs f32 (8 B/lane/edge) and halves the L2 working set.
// dstb != nullptr => also write bf16 shadow (for the next hop's gather).
__global__ __launch_bounds__(256) void spmm_k(
    const int* __restrict__ row_ptr, const int2* __restrict__ cv,
    const unsigned short* __restrict__ srcb, float* __restrict__ dst,
    unsigned short* __restrict__ dstb,
    const float* __restrict__ bias, int do_leaky,
    const unsigned char* __restrict__ flag, int n)
{
  int r = (blockIdx.x << 2) + (threadIdx.x >> 6);
  if (r >= n) return;
  if (flag && !flag[r]) return;
  const int lane = threadIdx.x & 63;
  const int c0 = lane << 2;
  int e0 = row_ptr[r], e1 = row_ptr[r + 1];
  float a0 = 0.f, a1 = 0.f, a2 = 0.f, a3 = 0.f;
  int e = e0;
  for (; e + 3 < e1; e += 4) {
    int2 p0 = cv[e], p1 = cv[e + 1], p2 = cv[e + 2], p3 = cv[e + 3];
    const ushort4 x0 = *reinterpret_cast<const ushort4*>(srcb + (size_t)p0.x * D_DIM + c0);
    const ushort4 x1 = *reinterpret_cast<const ushort4*>(srcb + (size_t)p1.x * D_DIM + c0);
    const ushort4 x2 = *reinterpret_cast<const ushort4*>(srcb + (size_t)p2.x * D_DIM + c0);
    const ushort4 x3 = *reinterpret_cast<const ushort4*>(srcb + (size_t)p3.x * D_DIM + c0);
    const float v0 = __int_as_float(p0.y), v1 = __int_as_float(p1.y);
    const float v2 = __int_as_float(p2.y), v3 = __int_as_float(p3.y);
    a0 = fmaf(v0, bf2f(x0.x), a0); a1 = fmaf(v0, bf2f(x0.y), a1);
    a2 = fmaf(v0, bf2f(x0.z), a2); a3 = fmaf(v0, bf2f(x0.w), a3);
    a0 = fmaf(v1, bf2f(x1.x), a0); a1 = fmaf(v1, bf2f(x1.y), a1);
    a2 = fmaf(v1, bf2f(x1.z), a2); a3 = fmaf(v1, bf2f(x1.w), a3);
    a0 = fmaf(v2, bf2f(x2.x), a0); a1 = fmaf(v2, bf2f(x2.y), a1);
    a2 = fmaf(v2, bf2f(x2.z), a2); a3 = fmaf(v2, bf2f(x2.w), a3);
    a0 = fmaf(v3, bf2f(x3.x), a0); a1 = fmaf(v3, bf2f(x3.y), a1);
    a2 = fmaf(v3, bf2f(x3.z), a2); a3 = fmaf(v3, bf2f(x3.w), a3);
  }
  for (; e < e1; ++e) {
    int2 p = cv[e];
    float v = __int_as_float(p.y);
    const ushort4 x = *reinterpret_cast<const ushort4*>(srcb + (size_t)p.x * D_DIM + c0);
    a0 = fmaf(v, bf2f(x.x), a0); a1 = fmaf(v, bf2f(x.y), a1);
    a2 = fmaf(v, bf2f(x.z), a2); a3 = fmaf(v, bf2f(x.w), a3);
  }
  if (bias) {
    const float4 b = *reinterpret_cast<const float4*>(bias + c0);
    a0 += b.x; a1 += b.y; a2 += b.z; a3 += b.w;
  }
  if (do_leaky) {
    a0 = a0 > 0.f ? a0 : 0.01f * a0;
    a1 = a1 > 0.f ? a1 : 0.01f * a1;
    a2 = a2 > 0.f ? a2 : 0.01f * a2;
    a3 = a3 > 0.f ? a3 : 0.01f * a3;
  }
  *reinterpret_cast<float4*>(dst + (size_t)r * D_DIM + c0) =
      make_float4(a0, a1, a2, a3);
  if (dstb) {
    ushort4 o;
    o.x = f2bf(a0); o.y = f2bf(a1); o.z = f2bf(a2); o.w = f2bf(a3);
    *reinterpret_cast<ushort4*>(dstb + (size_t)r * D_DIM + c0) = o;
  }
}

// ---------------- MFMA GEMM, split-precision bf16 (3-term), LDS B-staging ----
// 128-row tile, 512 threads (8 waves = 4M x 2N). Cb != nullptr => also write
// a bf16 shadow copy at [row*256+col] (for the next spmm's gather).
// MODE 0: C = A@W (+bias)      MODE 1: C = leaky(A@W + bias)
// MODE 2: g = sigmoid(A@W+bias); C = g*nxt[row] + (1-g)*hin[rowidx?rowidx[row]:row]
template<int KT, int MODE>
__global__ __launch_bounds__(512, 4) void mm_k(
    const float* __restrict__ Aptr,
    const unsigned short* __restrict__ Wt_hi,
    const unsigned short* __restrict__ Wt_lo,
    const float* __restrict__ bias,
    float* __restrict__ C, int ldc, int ccol0, int M,
    const int* __restrict__ rowidx,
    const float* __restrict__ nxt, const float* __restrict__ hin,
    unsigned short* __restrict__ Cb)
{
  __shared__ __align__(16) unsigned char smem[32768];  // hi: [0,16K), lo: [16K,32K)
  const int tid = threadIdx.x;
  const int wid = tid >> 6, lane = tid & 63;
  const int wm = wid & 3, wn = wid >> 2;       // 4 (M) x 2 (N) waves
  const int bm = blockIdx.x * 128;
  const int l15 = lane & 15, lk = lane >> 4;   // k-group 0..3

  int mrow[2];
  const float* arow[2];
#pragma unroll
  for (int mi = 0; mi < 2; ++mi) {
    int m = bm + wm * 32 + mi * 16 + l15;
    mrow[mi] = m;
    int sr = (m < M) ? (rowidx ? rowidx[m] : m) : 0;
    arow[mi] = Aptr + (size_t)sr * KT;
  }

  // staging: segment s in [0,1024): n=s>>2, k-seg=((s&3)-((s>>3)&3))&3
  const int s1 = tid, s2 = tid + 512;
  const size_t go1 = (size_t)(s1 >> 2) * KT + ((((s1 & 3) - ((s1 >> 3) & 3)) & 3) << 3);
  const size_t go2 = (size_t)(s2 >> 2) * KT + ((((s2 & 3) - ((s2 >> 3) & 3)) & 3) << 3);

  f32x4 acc[2][8] = {};
  for (int kc = 0; kc < KT / 32; ++kc) {
    const int kk = kc * 32;
    __syncthreads();   // previous chunk's reads complete before overwrite
    glds16(Wt_hi + go1 + kk, smem + s1 * 16);
    glds16(Wt_hi + go2 + kk, smem + s2 * 16);
    glds16(Wt_lo + go1 + kk, smem + 16384 + s1 * 16);
    glds16(Wt_lo + go2 + kk, smem + 16384 + s2 * 16);
    // A fragments (overlap with staging latency)
    const int ka = kk + lk * 8;
    bf16x8 ah[2], al[2];
#pragma unroll
    for (int mi = 0; mi < 2; ++mi) {
      bf16x8 th = {0, 0, 0, 0, 0, 0, 0, 0};
      bf16x8 tl = {0, 0, 0, 0, 0, 0, 0, 0};
      if (mrow[mi] < M) {
        const float* p = arow[mi] + ka;
        const float4 x = *reinterpret_cast<const float4*>(p);
        const float4 y = *reinterpret_cast<const float4*>(p + 4);
#define SPLIT_A(i, val) { unsigned short h_ = f2bf(val); th[i] = (short)h_; \
                          tl[i] = (short)f2bf((val) - bf2f(h_)); }
        SPLIT_A(0, x.x) SPLIT_A(1, x.y) SPLIT_A(2, x.z) SPLIT_A(3, x.w)
        SPLIT_A(4, y.x) SPLIT_A(5, y.y) SPLIT_A(6, y.z) SPLIT_A(7, y.w)
#undef SPLIT_A
      }
      ah[mi] = th; al[mi] = tl;
    }
    __syncthreads();   // staging drained (vmcnt(0)+barrier)
#pragma unroll
    for (int f = 0; f < 8; ++f) {
      const int n = wn * 128 + f * 16 + l15;
      const int boff = n * 64 + (((lk + (l15 >> 1)) & 3) << 4);
      const bf16x8 bh = *reinterpret_cast<const bf16x8*>(smem + boff);
      const bf16x8 bl = *reinterpret_cast<const bf16x8*>(smem + 16384 + boff);
#pragma unroll
      for (int mi = 0; mi < 2; ++mi) {
        acc[mi][f] = __builtin_amdgcn_mfma_f32_16x16x32_bf16(ah[mi], bh, acc[mi][f], 0, 0, 0);
        acc[mi][f] = __builtin_amdgcn_mfma_f32_16x16x32_bf16(al[mi], bh, acc[mi][f], 0, 0, 0);
        acc[mi][f] = __builtin_amdgcn_mfma_f32_16x16x32_bf16(ah[mi], bl, acc[mi][f], 0, 0, 0);
      }
    }
  }

  __syncthreads();   // in-place safety: all A reads in block done before writes

#pragma unroll
  for (int mi = 0; mi < 2; ++mi) {
    const int rbase = bm + wm * 32 + mi * 16 + lk * 4;
    int hsrc[4];
    if (MODE == 2) {
#pragma unroll
      for (int r = 0; r < 4; ++r) {
        const int row = rbase + r;
        hsrc[r] = (rowidx && row < M) ? rowidx[row] : row;
      }
    }
#pragma unroll
    for (int f = 0; f < 8; ++f) {
      const int col = wn * 128 + f * 16 + l15;
      const float bc = bias ? bias[col] : 0.f;
#pragma unroll
      for (int r = 0; r < 4; ++r) {
        const int row = rbase + r;
        if (row >= M) continue;
        float v = acc[mi][f][r] + bc;
        if (MODE == 1) v = v > 0.f ? v : 0.01f * v;
        if (MODE == 2) {
          const float g = 1.f / (1.f + __expf(-v));
          const float nv = nxt[(size_t)row * D_DIM + col];
          const float hv = hin[(size_t)hsrc[r] * D_DIM + col];
          v = g * nv + (1.f - g) * hv;
        }
        C[(size_t)row * ldc + ccol0 + col] = v;
        if (Cb) Cb[(size_t)row * D_DIM + col] = f2bf(v);
      }
    }
  }
}

// ---------------- row gather (f32 src -> f32 out columns) ----------------
__global__ __launch_bounds__(256) void gather_k(const float* __restrict__ src,
                                                const int* __restrict__ ids,
                                                float* __restrict__ dst, int ccol0, int B)
{
  int i = (blockIdx.x << 2) + (threadIdx.x >> 6);
  if (i >= B) return;
  const int lane = threadIdx.x & 63;
  const int c0 = lane << 2;
  const float4 v = *reinterpret_cast<const float4*>(src + (size_t)ids[i] * D_DIM + c0);
  *reinterpret_cast<float4*>(dst + (size_t)i * 1024 + ccol0 + c0) = v;
}

// ---------------- launch ----------------
extern "C" void kernel_launch(void* const* d_in, const int* in_sizes, int n_in,
                              void* d_out, int out_size, void* d_ws, size_t ws_size,
                              hipStream_t stream)
{
  const float* ent_lit = (const float*)d_in[0];
  const float* rel_lit = (const float*)d_in[1];
  const float* attr_lit = (const float*)d_in[2];
  const float* ent_val = (const float*)d_in[3];
  const float* rel_val = (const float*)d_in[4];
  const float* attr_val = (const float*)d_in[5];
  const float* W_ent = (const float*)d_in[6];
  const float* b_ent = (const float*)d_in[7];
  const float* W_rel = (const float*)d_in[8];
  const float* b_rel = (const float*)d_in[9];
  const float* W_attr = (const float*)d_in[10];
  const float* b_attr = (const float*)d_in[11];
  const float* W_x = (const float*)d_in[12];
  const float* b_x = (const float*)d_in[13];
  const float* W_lit = (const float*)d_in[14];
  const float* b_lit = (const float*)d_in[15];
  const float* W_gate = (const float*)d_in[16];
  const float* b_gate = (const float*)d_in[17];
  const int* ent_row = (const int*)d_in[18];
  const int* ent_col = (const int*)d_in[19];
  const int* rel_row = (const int*)d_in[20];
  const int* rel_col = (const int*)d_in[21];
  const int* attr_row = (const int*)d_in[22];
  const int* attr_col = (const int*)d_in[23];
  const int* ent_ids = (const int*)d_in[24];
  float* out = (float*)d_out;

  char* p = (char*)d_ws;
  const size_t bufsz = alignup((size_t)N_NODES * D_DIM * 4);
  const size_t bufszb = alignup((size_t)N_NODES * D_DIM * 2);
  const size_t wsz_f = alignup((size_t)F_DIM * D_DIM * 2);
  const size_t wsz_d = alignup((size_t)D_DIM * D_DIM * 2);
  float* B0 = (float*)p; p += bufsz;
  float* B1 = (float*)p; p += bufsz;
  unsigned short* B0b = (unsigned short*)p; p += bufszb;
  unsigned short* B1b = (unsigned short*)p; p += bufszb;
  float* P = (float*)B1b;  // aliases B1b: B1b dead once hop-3 spmm has run
  unsigned short* Wh_ent = (unsigned short*)p; p += wsz_f;
  unsigned short* Wl_ent = (unsigned short*)p; p += wsz_f;
  unsigned short* Wh_rel = (unsigned short*)p; p += wsz_f;
  unsigned short* Wl_rel = (unsigned short*)p; p += wsz_f;
  unsigned short* Wh_attr = (unsigned short*)p; p += wsz_f;
  unsigned short* Wl_attr = (unsigned short*)p; p += wsz_f;
  unsigned short* Wh_lit = (unsigned short*)p; p += wsz_f;
  unsigned short* Wl_lit = (unsigned short*)p; p += wsz_f;
  unsigned short* Wh_x = (unsigned short*)p; p += wsz_d;
  unsigned short* Wl_x = (unsigned short*)p; p += wsz_d;
  unsigned short* Wh_gate = (unsigned short*)p; p += wsz_d;
  unsigned short* Wl_gate = (unsigned short*)p; p += wsz_d;
  int* row_ptr3 = (int*)p; p += alignup((size_t)3 * (N_NODES + 1) * 4);
  int* bcnt = (int*)p; p += alignup((size_t)NB3 * 4);
  int* flatBase = (int*)p; p += alignup((size_t)(NB3 + 1) * 4);
  int* cursor = (int*)p; p += alignup((size_t)NB3 * 4);
  unsigned char* flags = (unsigned char*)p; p += alignup((size_t)N_NODES);
  int2* cv3 = (int2*)p; p += alignup((size_t)3 * N_EDGES * 8);
  if ((size_t)(p - (char*)d_ws) > ws_size) return;

  // packed edge buffer aliases B0 (dead until first mm_k, which runs after bfinal)
  int2* packed = (int2*)B0;

  const int* rp_ent = row_ptr3;
  const int* rp_rel = row_ptr3 + (N_NODES + 1);
  const int* rp_attr = row_ptr3 + 2 * (N_NODES + 1);
  const int2* cv_ent = cv3;
  const int2* cv_rel = cv3 + (size_t)N_EDGES;
  const int2* cv_attr = cv3 + (size_t)2 * N_EDGES;

  dim3 blk(256), blk512(512);
  const int nchunks = (int)((3LL * N_EDGES + CHUNK - 1) / CHUNK);
  dim3 g_spmm((N_NODES + 3) / 4);
  dim3 g_gather((B_IDS + 3) / 4);
  dim3 g_mm_big((N_NODES + 127) / 128);
  dim3 g_mm_ids(B_IDS / 128);

  // weights -> bf16 hi/lo transposed (one fused launch)
  TrArgs ta;
  ta.W[0] = W_ent;  ta.Wh[0] = Wh_ent;  ta.Wl[0] = Wl_ent;  ta.K[0] = F_DIM;
  ta.W[1] = W_rel;  ta.Wh[1] = Wh_rel;  ta.Wl[1] = Wl_rel;  ta.K[1] = F_DIM;
  ta.W[2] = W_attr; ta.Wh[2] = Wh_attr; ta.Wl[2] = Wl_attr; ta.K[2] = F_DIM;
  ta.W[3] = W_lit;  ta.Wh[3] = Wh_lit;  ta.Wl[3] = Wl_lit;  ta.K[3] = F_DIM;
  ta.W[4] = W_x;    ta.Wh[4] = Wh_x;    ta.Wl[4] = Wl_x;    ta.K[4] = D_DIM;
  ta.W[5] = W_gate; ta.Wh[5] = Wh_gate; ta.Wl[5] = Wl_gate; ta.K[5] = D_DIM;
  tr_all_k<<<dim3(F_DIM / 64, 4, 6), blk, 0, stream>>>(ta);

  // CSR build (bucket sort)
  hipMemsetAsync(bcnt, 0, NB3 * sizeof(int), stream);
  bcount_k<<<dim3(nchunks), blk, 0, stream>>>(ent_row, rel_row, attr_row, bcnt);
  bscan_k<<<dim3(1), blk, 0, stream>>>(bcnt, flatBase, cursor);
  bpart_k<<<dim3(nchunks), blk, 0, stream>>>(ent_row, ent_col, ent_val,
                                             rel_row, rel_col, rel_val,
                                             attr_row, attr_col, attr_val,
                                             cursor, packed);
  bfinal_k<<<dim3(NB3), blk, 0, stream>>>(packed, flatBase, row_ptr3, cv3);

  // flags for row restriction (rows observed via ent_ids)
  hipMemsetAsync(flags, 0, N_NODES, stream);
  flag_k<<<dim3(B_IDS / 256), blk, 0, stream>>>(ent_ids, flags, B_IDS);

  // ----- rel branch -> out[:,512:768]
  mm_k<F_DIM, 0><<<g_mm_big, blk512, 0, stream>>>(rel_lit, Wh_rel, Wl_rel, nullptr, B0, D_DIM, 0,
                                                  N_NODES, nullptr, nullptr, nullptr, B0b);
  spmm_k<<<g_spmm, blk, 0, stream>>>(rp_rel, cv_rel, B0b, B1, nullptr, b_rel, 1, flags, N_NODES);
  gather_k<<<g_gather, blk, 0, stream>>>(B1, ent_ids, out, 512, B_IDS);

  // ----- attr branch -> out[:,768:1024]
  mm_k<F_DIM, 0><<<g_mm_big, blk512, 0, stream>>>(attr_lit, Wh_attr, Wl_attr, nullptr, B0, D_DIM, 0,
                                                  N_NODES, nullptr, nullptr, nullptr, B0b);
  spmm_k<<<g_spmm, blk, 0, stream>>>(rp_attr, cv_attr, B0b, B1, nullptr, b_attr, 1, flags, N_NODES);
  gather_k<<<g_gather, blk, 0, stream>>>(B1, ent_ids, out, 768, B_IDS);

  // ----- ent literals -> out[:,0:256]
  mm_k<F_DIM, 0><<<g_mm_ids, blk512, 0, stream>>>(ent_lit, Wh_lit, Wl_lit, b_lit, out, 1024, 0,
                                                  B_IDS, ent_ids, nullptr, nullptr, nullptr);

  // ----- ent n-hop -----
  mm_k<F_DIM, 0><<<g_mm_big, blk512, 0, stream>>>(ent_lit, Wh_ent, Wl_ent, nullptr, B0, D_DIM, 0,
                                                  N_NODES, nullptr, nullptr, nullptr, B0b);
  // h1 = leaky(spmm + b): f32 -> B1, bf16 shadow -> B1b
  spmm_k<<<g_spmm, blk, 0, stream>>>(rp_ent, cv_ent, B0b, B1, B1b, b_ent, 1, nullptr, N_NODES);
  // hop 2: s2 = spmm(h1) -> B0 (f32 only)
  spmm_k<<<g_spmm, blk, 0, stream>>>(rp_ent, cv_ent, B1b, B0, nullptr, nullptr, 0, nullptr, N_NODES);
  mm_k<D_DIM, 1><<<g_mm_big, blk512, 0, stream>>>(B0, Wh_x, Wl_x, b_x, B0, D_DIM, 0,
                                                  N_NODES, nullptr, nullptr, nullptr, nullptr); // nxt2=B0
  mm_k<D_DIM, 2><<<g_mm_big, blk512, 0, stream>>>(B1, Wh_gate, Wl_gate, b_gate, B1, D_DIM, 0,
                                                  N_NODES, nullptr, B0, B1, B1b);               // h2=B1(+B1b)
  // hop 3 (only rows observed via ent_ids): s3 = spmm(h2) -> B0 (flagged)
  spmm_k<<<g_spmm, blk, 0, stream>>>(rp_ent, cv_ent, B1b, B0, nullptr, nullptr, 0, flags, N_NODES);
  mm_k<D_DIM, 1><<<g_mm_ids, blk512, 0, stream>>>(B0, Wh_x, Wl_x, b_x, P, D_DIM, 0,
                                                  B_IDS, ent_ids, nullptr, nullptr, nullptr);   // nxt3 (P aliases B1b)
  mm_k<D_DIM, 2><<<g_mm_ids, blk512, 0, stream>>>(B1, Wh_gate, Wl_gate, b_gate, out, 1024, 256,
                                                  B_IDS, ent_ids, P, B1, nullptr);              // -> out[:,256:512]
}